// Round 9
// baseline (830.745 us; speedup 1.0000x reference)
//
#include <hip/hip_runtime.h>
#include <hip/hip_bf16.h>
#include <stdint.h>

// Castle attention, bf16 MFMA pipeline, fused-generation version.
// convert -> qkv GEMM (gld16 dbuf, slab epilogue) -> vcT transpose
//   -> castle (per (I,K) tile: GEN term1/look on the fly -> Su -> -silu -> +Sc
//              -> mask -> local softmax -> PV partials)  [no tl kernel, no packed buffers]
//   -> combine (flash-merge) -> out GEMM.

typedef unsigned short u16;
typedef __attribute__((ext_vector_type(8))) short s8v;   // 8 x bf16
typedef __attribute__((ext_vector_type(4))) float f4v;   // MFMA accumulator

#define LDS_STRIDE 40

__device__ __forceinline__ u16 f2bf(float f) {
  union { float f; unsigned u; } v; v.f = f;
  unsigned r = v.u + 0x7FFFu + ((v.u >> 16) & 1u);
  return (u16)(r >> 16);
}
__device__ __forceinline__ float bf2f(u16 u) {
  union { unsigned u; float f; } v; v.u = ((unsigned)u) << 16; return v.f;
}

typedef __attribute__((address_space(1))) const void* gas_t;
typedef __attribute__((address_space(3))) void* las_t;
__device__ __forceinline__ void gld16(const void* g, void* l) {
  __builtin_amdgcn_global_load_lds((gas_t)g, (las_t)l, 16, 0, 0);
}

__device__ __forceinline__ void stage_tile(u16* __restrict__ dst, const u16* __restrict__ src,
                                           int rows, long srcStride, int tid, int nthreads) {
  for (int i = tid; i < rows * 4; i += nthreads) {
    int r = i >> 2, seg = i & 3;
    *(uint4*)(&dst[r * LDS_STRIDE + seg * 8]) =
        *(const uint4*)(&src[(long)r * srcStride + seg * 8]);
  }
}

__device__ __forceinline__ void mfma_tile(const u16* As, const u16* Bs, int lane,
                                          int wm, int wn, f4v acc[4][4]) {
  const int rl = lane & 15;
  const int ks = (lane >> 4) * 8;
  s8v a[4], b[4];
#pragma unroll
  for (int m = 0; m < 4; ++m)
    a[m] = *(const s8v*)(&As[(wm * 64 + m * 16 + rl) * LDS_STRIDE + ks]);
#pragma unroll
  for (int n = 0; n < 4; ++n)
    b[n] = *(const s8v*)(&Bs[(wn * 64 + n * 16 + rl) * LDS_STRIDE + ks]);
#pragma unroll
  for (int m = 0; m < 4; ++m)
#pragma unroll
    for (int n = 0; n < 4; ++n)
      acc[m][n] = __builtin_amdgcn_mfma_f32_16x16x32_bf16(a[m], b[n], acc[m][n], 0, 0, 0);
}

__device__ __forceinline__ void zero_acc(f4v acc[4][4]) {
  f4v z = {0.f, 0.f, 0.f, 0.f};
#pragma unroll
  for (int m = 0; m < 4; ++m)
#pragma unroll
    for (int n = 0; n < 4; ++n) acc[m][n] = z;
}

// ---------------- converts ----------------

__global__ void convert_x_kernel(const float* __restrict__ in, u16* __restrict__ out) {
  int i = (blockIdx.x * 256 + threadIdx.x) * 4;
  float4 v = *(const float4*)(&in[i]);
  out[i + 0] = f2bf(v.x);
  out[i + 1] = f2bf(v.y);
  out[i + 2] = f2bf(v.z);
  out[i + 3] = f2bf(v.w);
}

__global__ void transpose_convert_kernel(const float* __restrict__ in, u16* __restrict__ out,
                                         int R, int C) {
  __shared__ float tile[32][33];
  int c0 = blockIdx.x * 32, r0 = blockIdx.y * 32;
  for (int rr = threadIdx.y; rr < 32; rr += 8)
    tile[rr][threadIdx.x] = in[(size_t)(r0 + rr) * C + (c0 + threadIdx.x)];
  __syncthreads();
  for (int cc = threadIdx.y; cc < 32; cc += 8)
    out[(size_t)(c0 + cc) * R + (r0 + threadIdx.x)] = f2bf(tile[threadIdx.x][cc]);
}

// ---------------- qkv projection: gld16 dbuf staging + LDS slab epilogue ----------------

__global__ __launch_bounds__(256, 2) void gemm_qkv_kernel(
    const u16* __restrict__ xb, const u16* __restrict__ wqkvT,
    u16* __restrict__ quS, u16* __restrict__ ku, u16* __restrict__ vu,
    u16* __restrict__ qcS, u16* __restrict__ kc, u16* __restrict__ vcN) {
  __shared__ u16 sA[2][8192];  // [128][64-swz] per buf
  __shared__ u16 sB[2][8192];
  int bm = blockIdx.x, bn = blockIdx.y;
  int tid = threadIdx.x, lane = tid & 63, w = tid >> 6, wm = w >> 1, wn = w & 1;
  int g = lane >> 4, l15 = lane & 15;
  const int sz = (l15 & 7) << 3;
  const int bo = tid * 16;

  const u16* Ab = xb + (size_t)(bm * 128) * 1024;
  const u16* Bb = wqkvT + (size_t)(bn * 128) * 1024;

  auto stg = [&](const u16* base, int ks, u16* dst) {
#pragma unroll
    for (int it = 0; it < 4; ++it) {
      int o = bo + it * 4096;
      int row = o >> 7, lo = o & 127;
      gld16(base + (size_t)row * 1024 + ks * 64 + ((lo ^ ((row & 7) << 4)) >> 1),
            (char*)dst + o);
    }
  };

  f4v acc[4][4];
  zero_acc(acc);
  stg(Ab, 0, sA[0]);
  stg(Bb, 0, sB[0]);
  stg(Ab, 1, sA[1]);
  stg(Bb, 1, sB[1]);

  for (int ks = 0; ks < 16; ++ks) {
    int buf = ks & 1;
    if (ks < 15)
      asm volatile("s_waitcnt vmcnt(8)" ::: "memory");
    else
      asm volatile("s_waitcnt vmcnt(0)" ::: "memory");
    __builtin_amdgcn_sched_barrier(0);
    __builtin_amdgcn_s_barrier();
    __builtin_amdgcn_sched_barrier(0);
#pragma unroll
    for (int kk = 0; kk < 2; ++kk) {
      int c2 = kk * 32 + g * 8;
      s8v a[4], b[4];
#pragma unroll
      for (int m = 0; m < 4; ++m)
        a[m] = *(const s8v*)(&sA[buf][(wm * 64 + m * 16 + l15) * 64 + (c2 ^ sz)]);
#pragma unroll
      for (int n = 0; n < 4; ++n)
        b[n] = *(const s8v*)(&sB[buf][(wn * 64 + n * 16 + l15) * 64 + (c2 ^ sz)]);
#pragma unroll
      for (int m = 0; m < 4; ++m)
#pragma unroll
        for (int n = 0; n < 4; ++n)
          acc[m][n] = __builtin_amdgcn_mfma_f32_16x16x32_bf16(a[m], b[n], acc[m][n], 0, 0, 0);
    }
    __builtin_amdgcn_s_barrier();
    if (ks + 2 < 16) {
      stg(Ab, ks + 2, sA[buf]);
      stg(Bb, ks + 2, sB[buf]);
    }
  }

  // slab epilogue: per pass one head's 128x64 contiguous slab
  int s = bn >> 3;
  int b = bm >> 4;
  int nn0 = (bm & 15) * 128;
  int hh0 = (bn & 7) * 2;
  float scale = (s == 0 || s == 3) ? 0.125f : 1.f;
  u16* obase;
  switch (s) {
    case 0: obase = quS; break;
    case 1: obase = ku; break;
    case 2: obase = vu; break;
    case 3: obase = qcS; break;
    case 4: obase = kc; break;
    default: obase = vcN; break;
  }
  u16* sE = (u16*)sA;
#pragma unroll
  for (int pass = 0; pass < 2; ++pass) {
    __syncthreads();
    if (wn == pass) {
#pragma unroll
      for (int m = 0; m < 4; ++m)
#pragma unroll
        for (int n = 0; n < 4; ++n)
#pragma unroll
          for (int j = 0; j < 4; ++j) {
            int lrow = wm * 64 + m * 16 + g * 4 + j;
            int d = n * 16 + l15;
            sE[lrow * 64 + d] = f2bf(acc[m][n][j] * scale);
          }
    }
    __syncthreads();
    int bh = (b << 4) + hh0 + pass;
    u16* dst = obase + ((size_t)bh * 2048 + nn0) * 64;
    for (int it = 0; it < 4; ++it) {
      int e = (tid + it * 256) * 8;
      *(uint4*)(dst + e) = *(const uint4*)(&sE[e]);
    }
  }
}

// ------------- vcN [bh][n][d] -> vcT [bh][d][n] -------------

__global__ __launch_bounds__(256) void transpose_v_kernel(const u16* __restrict__ vcN,
                                                          u16* __restrict__ vcT) {
  __shared__ u16 t[64][72];
  int nt = blockIdx.x, bh = blockIdx.y;
  const u16* src = vcN + ((size_t)bh * 2048 + nt * 64) * 64;
  int tid = threadIdx.x;
  for (int i = tid; i < 512; i += 256) {
    int r = i >> 3, cseg = i & 7;
    *(uint4*)(&t[r][cseg * 8]) = *(const uint4*)(src + r * 64 + cseg * 8);
  }
  __syncthreads();
  u16* dst = vcT + (size_t)bh * 64 * 2048 + nt * 64;
  for (int i = tid; i < 512; i += 256) {
    int d = i >> 3, nseg = i & 7;
    u16 tmp[8];
#pragma unroll
    for (int e = 0; e < 8; ++e) tmp[e] = t[nseg * 8 + e][d];
    *(uint4*)(dst + (size_t)d * 2048 + nseg * 8) = *(uint4*)tmp;
  }
}

// ------------- castle (fused gen): per (I,K) tile -------------
// j-loop: GEN term1(I,j) from qc[I] (regs) x vu[j] (direct global), mask;
//         GEN look(K,j) from qu[K] (regs) x ku[j], sigmoid+mask;
//         both -> LDS [half][128][64-swz]; Su += term1 @ look^T.
// Tail: Sc (kc via gld16), causal mask, softmax, P->LDS, PV (vcT via gld16), partials.

__global__ __launch_bounds__(256, 2) void castle_kernel(
    const u16* __restrict__ quS, const u16* __restrict__ ku,
    const u16* __restrict__ vu, const u16* __restrict__ qcS,
    const u16* __restrict__ kc, const u16* __restrict__ vcT,
    u16* __restrict__ opart, float* __restrict__ ml) {
  __shared__ u16 sT[16384];  // term1 tile [2 halves][128][64-swz]; later P
  __shared__ u16 sL[16384];  // look tile; later [Vs | Ks]
  int bid = blockIdx.x;
  int lb = bid / 136, sid = bid % 136;
  int bh = lb;
  int I = 15, rem = sid;
  while (rem > I) { rem -= I + 1; --I; }
  int K = rem;
  int t = I * (I + 1) / 2 + K;

  int tid = threadIdx.x, lane = tid & 63, w = tid >> 6;
  int g = lane >> 4, l15 = lane & 15;
  const int sz = (l15 & 7) << 3;
  const int bo = tid * 16;

  // qc[I] / qu[K] row fragments (A-operands for gen, qa also for Sc)
  s8v qa[2][2], qua[2][2];
#pragma unroll
  for (int mg = 0; mg < 2; ++mg)
#pragma unroll
    for (int kk = 0; kk < 2; ++kk) {
      qa[mg][kk] = *(const s8v*)(&qcS[((size_t)bh * 2048 + I * 128 + w * 32 + mg * 16 + l15) * 64 +
                                      kk * 32 + g * 8]);
      qua[mg][kk] = *(const s8v*)(&quS[((size_t)bh * 2048 + K * 128 + w * 32 + mg * 16 + l15) * 64 +
                                       kk * 32 + g * 8]);
    }

  f4v su[2][8];
  {
    f4v z = {0.f, 0.f, 0.f, 0.f};
#pragma unroll
    for (int mg = 0; mg < 2; ++mg)
#pragma unroll
      for (int n = 0; n < 8; ++n) su[mg][n] = z;
  }

  for (int jt = K; jt <= I; ++jt) {
    const u16* vub = vu + ((size_t)bh * 2048 + jt * 128) * 64;
    const u16* kub = ku + ((size_t)bh * 2048 + jt * 128) * 64;
    // ---- 4 gen phases: {term1,look} x {col-half 0,1} ----
#pragma unroll
    for (int ph = 0; ph < 4; ++ph) {
      const int isL = ph >> 1, hf = ph & 1;
      const u16* src = isL ? kub : vub;
      f4v acc[2][4];
      {
        f4v z = {0.f, 0.f, 0.f, 0.f};
#pragma unroll
        for (int mg = 0; mg < 2; ++mg)
#pragma unroll
          for (int n = 0; n < 4; ++n) acc[mg][n] = z;
      }
#pragma unroll
      for (int kk = 0; kk < 2; ++kk) {
        s8v b[4];
#pragma unroll
        for (int n = 0; n < 4; ++n)
          b[n] = *(const s8v*)(&src[(hf * 64 + n * 16 + l15) * 64 + kk * 32 + g * 8]);
#pragma unroll
        for (int mg = 0; mg < 2; ++mg) {
          s8v af = isL ? qua[mg][kk] : qa[mg][kk];
#pragma unroll
          for (int n = 0; n < 4; ++n)
            acc[mg][n] = __builtin_amdgcn_mfma_f32_16x16x32_bf16(af, b[n], acc[mg][n], 0, 0, 0);
        }
      }
      u16* dstl = isL ? sL : sT;
#pragma unroll
      for (int mg = 0; mg < 2; ++mg)
#pragma unroll
        for (int n = 0; n < 4; ++n)
#pragma unroll
          for (int q = 0; q < 4; ++q) {
            int lr = w * 32 + mg * 16 + g * 4 + q;
            int lc = n * 16 + l15;  // 0..63 within half
            float v = acc[mg][n][q];
            if (isL) {
              v = 1.f / (1.f + __expf(-v));                      // sigmoid
              if (jt == K && (hf * 64 + lc) <= lr) v = 0.f;      // strict upper only
            } else {
              if (jt == I && (hf * 64 + lc) > lr) v = 0.f;       // lower incl diag
            }
            dstl[hf * 8192 + lr * 64 + (lc ^ ((lr & 7) << 3))] = f2bf(v);
          }
    }
    asm volatile("s_waitcnt lgkmcnt(0)" ::: "memory");
    __builtin_amdgcn_sched_barrier(0);
    __builtin_amdgcn_s_barrier();
    __builtin_amdgcn_sched_barrier(0);
    // ---- Su += term1 @ look^T over this j-tile (K=128) ----
#pragma unroll
    for (int ks = 0; ks < 4; ++ks) {
      int half = ks >> 1, c2 = (ks & 1) * 32 + g * 8;
      s8v a[2], b[8];
      a[0] = *(const s8v*)(&sT[half * 8192 + (w * 32 + l15) * 64 + (c2 ^ sz)]);
      a[1] = *(const s8v*)(&sT[half * 8192 + (w * 32 + 16 + l15) * 64 + (c2 ^ sz)]);
#pragma unroll
      for (int n = 0; n < 8; ++n)
        b[n] = *(const s8v*)(&sL[half * 8192 + (n * 16 + l15) * 64 + (c2 ^ sz)]);
#pragma unroll
      for (int mg = 0; mg < 2; ++mg)
#pragma unroll
        for (int n = 0; n < 8; ++n)
          su[mg][n] = __builtin_amdgcn_mfma_f32_16x16x32_bf16(a[mg], b[n], su[mg][n], 0, 0, 0);
    }
    __builtin_amdgcn_s_barrier();  // readers done before next j's gen overwrites
  }

  // ---- stage Vs (sL bytes [0,16K)) and Ks (sL bytes [16K,32K)), overlap with silu ----
  {
#pragma unroll
    for (int it = 0; it < 4; ++it) {
      int o = bo + it * 4096;
      int kh = o >> 13, oc = o & 8191;
      int dr = oc >> 7, lo = oc & 127;
      const u16* src = vcT + ((size_t)bh * 64 + dr) * 2048 + K * 128 + kh * 64 +
                       ((lo ^ ((dr & 7) << 4)) >> 1);
      gld16(src, (char*)sL + o);
    }
#pragma unroll
    for (int it = 0; it < 4; ++it) {
      int o = bo + it * 4096;
      int row = o >> 7, lo = o & 127;
      const u16* src = kc + ((size_t)bh * 2048 + K * 128 + row) * 64 +
                       ((lo ^ ((row & 7) << 4)) >> 1);
      gld16(src, (char*)sL + 16384 + o);
    }
  }
  // su = -silu(su) while loads fly
#pragma unroll
  for (int mg = 0; mg < 2; ++mg)
#pragma unroll
    for (int n = 0; n < 8; ++n)
#pragma unroll
      for (int j4 = 0; j4 < 4; ++j4) {
        float xv = su[mg][n][j4];
        su[mg][n][j4] = -(xv / (1.f + __expf(-xv)));
      }
  __syncthreads();  // drains vmcnt: Vs/Ks ready

  // ---- Sc accumulate (Ks at sL elems [8192,16384)) ----
#pragma unroll
  for (int kk = 0; kk < 2; ++kk) {
    int c = kk * 32 + g * 8;
    s8v b[8];
#pragma unroll
    for (int n = 0; n < 8; ++n)
      b[n] = *(const s8v*)(&sL[8192 + (n * 16 + l15) * 64 + (c ^ sz)]);
#pragma unroll
    for (int mg = 0; mg < 2; ++mg)
#pragma unroll
      for (int n = 0; n < 8; ++n)
        su[mg][n] = __builtin_amdgcn_mfma_f32_16x16x32_bf16(qa[mg][kk], b[n], su[mg][n], 0, 0, 0);
  }

  // ---- causal mask (diagonal tile only) ----
  if (K == I) {
#pragma unroll
    for (int mg = 0; mg < 2; ++mg)
#pragma unroll
      for (int n = 0; n < 8; ++n)
#pragma unroll
        for (int j4 = 0; j4 < 4; ++j4) {
          int lr = w * 32 + mg * 16 + g * 4 + j4;
          int lc = n * 16 + l15;
          if (lc > lr) su[mg][n][j4] = -3.0e38f;
        }
  }

  // ---- local softmax; P -> sT as [kh][128][64-swz] ----
  float mrow[2][4], lrow[2][4];
#pragma unroll
  for (int mg = 0; mg < 2; ++mg)
#pragma unroll
    for (int j4 = 0; j4 < 4; ++j4) {
      float v = -3.0e38f;
#pragma unroll
      for (int n = 0; n < 8; ++n) v = fmaxf(v, su[mg][n][j4]);
      v = fmaxf(v, __shfl_xor(v, 1));
      v = fmaxf(v, __shfl_xor(v, 2));
      v = fmaxf(v, __shfl_xor(v, 4));
      v = fmaxf(v, __shfl_xor(v, 8));
      mrow[mg][j4] = v;
    }
#pragma unroll
  for (int mg = 0; mg < 2; ++mg)
#pragma unroll
    for (int j4 = 0; j4 < 4; ++j4) {
      float sum = 0.f;
      int prow = w * 32 + mg * 16 + g * 4 + j4;
      int psz = ((g * 4 + j4) & 7) << 3;
#pragma unroll
      for (int n = 0; n < 8; ++n) {
        float e = __expf(su[mg][n][j4] - mrow[mg][j4]);
        sum += e;
        int pc = n * 16 + l15;
        sT[(n >> 2) * 8192 + prow * 64 + ((pc & 63) ^ psz)] = f2bf(e);
      }
      sum += __shfl_xor(sum, 1);
      sum += __shfl_xor(sum, 2);
      sum += __shfl_xor(sum, 4);
      sum += __shfl_xor(sum, 8);
      lrow[mg][j4] = sum;
    }
  __syncthreads();

  // ---- PV: O = P @ Vs ----
  f4v o[2][4];
  {
    f4v z = {0.f, 0.f, 0.f, 0.f};
#pragma unroll
    for (int mg = 0; mg < 2; ++mg)
#pragma unroll
      for (int nd = 0; nd < 4; ++nd) o[mg][nd] = z;
  }
#pragma unroll
  for (int kk = 0; kk < 4; ++kk) {
    int kh = kk >> 1;
    int cc = (kk & 1) * 32 + g * 8;
    s8v pa[2], vb[4];
#pragma unroll
    for (int mg = 0; mg < 2; ++mg)
      pa[mg] = *(const s8v*)(&sT[kh * 8192 + (w * 32 + mg * 16 + l15) * 64 + (cc ^ sz)]);
#pragma unroll
    for (int nd = 0; nd < 4; ++nd)
      vb[nd] = *(const s8v*)(&sL[kh * 4096 + (nd * 16 + l15) * 64 + (cc ^ sz)]);
#pragma unroll
    for (int mg = 0; mg < 2; ++mg)
#pragma unroll
      for (int nd = 0; nd < 4; ++nd)
        o[mg][nd] = __builtin_amdgcn_mfma_f32_16x16x32_bf16(pa[mg], vb[nd], o[mg][nd], 0, 0, 0);
  }

  // ---- write partials ----
  size_t tb = (size_t)lb * 136 + t;
#pragma unroll
  for (int mg = 0; mg < 2; ++mg)
#pragma unroll
    for (int nd = 0; nd < 4; ++nd)
#pragma unroll
      for (int j4 = 0; j4 < 4; ++j4) {
        int prow = w * 32 + mg * 16 + g * 4 + j4;
        int dcol = nd * 16 + l15;
        opart[(tb * 128 + prow) * 64 + dcol] = f2bf(o[mg][nd][j4]);
      }
  if (l15 == 0) {
#pragma unroll
    for (int mg = 0; mg < 2; ++mg)
#pragma unroll
      for (int j4 = 0; j4 < 4; ++j4) {
        int prow = w * 32 + mg * 16 + g * 4 + j4;
        ml[tb * 256 + prow] = mrow[mg][j4];
        ml[tb * 256 + 128 + prow] = lrow[mg][j4];
      }
  }
}

// ------------- combine: flash-merge the <=16 partials per (I, head) -------------

__global__ __launch_bounds__(256) void combine_kernel(const u16* __restrict__ opart,
                                                      const float* __restrict__ ml,
                                                      u16* __restrict__ attn) {
  int lb = blockIdx.x, I = blockIdx.y, bh = lb;
  int tid = threadIdx.x;
  int row = tid >> 1, dh = (tid & 1) << 5;
  float M = -3.0e38f, L = 0.f;
  float O[32];
#pragma unroll
  for (int i = 0; i < 32; ++i) O[i] = 0.f;
  for (int K = 0; K <= I; ++K) {
    size_t tb = (size_t)lb * 136 + I * (I + 1) / 2 + K;
    float m = ml[tb * 256 + row];
    float l = ml[tb * 256 + 128 + row];
    float newM = fmaxf(M, m);
    float so = __expf(M - newM), sn = __expf(m - newM);
    L = L * so + l * sn;
    const u16* op = opart + (tb * 128 + row) * 64 + dh;
#pragma unroll
    for (int q = 0; q < 4; ++q) {
      s8v ov = *(const s8v*)(op + q * 8);
#pragma unroll
      for (int e = 0; e < 8; ++e)
        O[q * 8 + e] = O[q * 8 + e] * so + bf2f((u16)ov[e]) * sn;
    }
    M = newM;
  }
  float inv = 1.f / L;
  int b = bh >> 4, hh = bh & 15;
  u16* dst = attn + ((size_t)b * 2048 + I * 128 + row) * 1024 + hh * 64 + dh;
#pragma unroll
  for (int i = 0; i < 32; ++i) dst[i] = f2bf(O[i] * inv);
}

// ------------- final: out = attn_out @ W_out, f32 -------------

__global__ __launch_bounds__(256) void gemm_out_kernel(const u16* __restrict__ attn,
                                                       const u16* __restrict__ woutT,
                                                       float* __restrict__ out) {
  __shared__ u16 sh[10240];
  u16* As = sh;
  u16* Bs = sh + 5120;
  int bm = blockIdx.x, bn = blockIdx.y;
  int tid = threadIdx.x, lane = tid & 63, w = tid >> 6, wm = w >> 1, wn = w & 1;
  f4v acc[4][4];
  zero_acc(acc);
  for (int kk = 0; kk < 1024; kk += 32) {
    stage_tile(As, attn + (size_t)(bm * 128) * 1024 + kk, 128, 1024, tid, 256);
    stage_tile(Bs, woutT + (size_t)(bn * 128) * 1024 + kk, 128, 1024, tid, 256);
    __syncthreads();
    mfma_tile(As, Bs, lane, wm, wn, acc);
    __syncthreads();
  }
#pragma unroll
  for (int m = 0; m < 4; ++m)
#pragma unroll
    for (int n = 0; n < 4; ++n)
#pragma unroll
      for (int j = 0; j < 4; ++j) {
        int row = bm * 128 + wm * 64 + m * 16 + ((lane >> 4) * 4) + j;
        int col = bn * 128 + wn * 64 + n * 16 + (lane & 15);
        out[(size_t)row * 1024 + col] = acc[m][n][j];
      }
}

// ---------------- host ----------------

extern "C" void kernel_launch(void* const* d_in, const int* in_sizes, int n_in,
                              void* d_out, int out_size, void* d_ws, size_t ws_size,
                              hipStream_t stream) {
  const float* x = (const float*)d_in[0];
  const float* Wqkv = (const float*)d_in[1];
  const float* Wout = (const float*)d_in[2];
  float* out = (float*)d_out;

  char* base = (char*)d_ws;
  size_t off = 0;
  auto alloc = [&](size_t bytes) -> void* {
    void* p = base + off;
    off += (bytes + 255) & ~(size_t)255;
    return p;
  };

  u16* woutT = (u16*)alloc(1024ull * 1024 * 2);
  u16* quS = (u16*)alloc(32ull * 2048 * 64 * 2);
  u16* ku = (u16*)alloc(32ull * 2048 * 64 * 2);
  u16* vu = (u16*)alloc(32ull * 2048 * 64 * 2);
  u16* qcS = (u16*)alloc(32ull * 2048 * 64 * 2);
  u16* kc = (u16*)alloc(32ull * 2048 * 64 * 2);
  u16* vcN = (u16*)alloc(32ull * 2048 * 64 * 2);
  u16* vcT = (u16*)alloc(32ull * 2048 * 64 * 2);
  u16* attn = (u16*)alloc(4096ull * 1024 * 2);
  u16* opart = (u16*)alloc(32ull * 136 * 8192 * 2);   // ~71 MB
  float* mlb = (float*)alloc(32ull * 136 * 256 * 4);  // ~4.5 MB
  u16* xb = (u16*)alloc(4096ull * 1024 * 2);
  u16* wqkvT = (u16*)alloc(6144ull * 1024 * 2);

  convert_x_kernel<<<4096, 256, 0, stream>>>(x, xb);
  transpose_convert_kernel<<<dim3(192, 32), dim3(32, 8), 0, stream>>>(Wqkv, wqkvT, 1024, 6144);
  transpose_convert_kernel<<<dim3(32, 32), dim3(32, 8), 0, stream>>>(Wout, woutT, 1024, 1024);
  gemm_qkv_kernel<<<dim3(32, 48), 256, 0, stream>>>(xb, wqkvT, quS, ku, vu, qcS, kc, vcN);
  transpose_v_kernel<<<dim3(32, 32), 256, 0, stream>>>(vcN, vcT);

  castle_kernel<<<dim3(136 * 32), 256, 0, stream>>>(quS, ku, vu, qcS, kc, vcT, opart, mlb);
  combine_kernel<<<dim3(32, 16), 256, 0, stream>>>(opart, mlb, attn);
  gemm_out_kernel<<<dim3(32, 8), 256, 0, stream>>>(attn, woutT, out);
}

// Round 10
// 602.126 us; speedup vs baseline: 1.3797x; 1.3797x over previous
//
#include <hip/hip_runtime.h>
#include <hip/hip_bf16.h>
#include <stdint.h>

// Castle attention, bf16 MFMA pipeline, consolidated best-of config.
// convert -> qkv GEMM (gld16 dbuf, slab epilogue) -> vcT transpose
//   -> tl (per-tile, packed swizzled half-tiles, coalesced writes)   [gen paid once]
//   -> castle (dbuf prefetch j-loop: Su -> -silu -> +Sc -> mask -> softmax -> PV)
//   -> combine (flash-merge) -> out GEMM (gld16 dbuf).

typedef unsigned short u16;
typedef __attribute__((ext_vector_type(8))) short s8v;   // 8 x bf16
typedef __attribute__((ext_vector_type(4))) float f4v;   // MFMA accumulator

__device__ __forceinline__ u16 f2bf(float f) {
  union { float f; unsigned u; } v; v.f = f;
  unsigned r = v.u + 0x7FFFu + ((v.u >> 16) & 1u);
  return (u16)(r >> 16);
}
__device__ __forceinline__ float bf2f(u16 u) {
  union { unsigned u; float f; } v; v.u = ((unsigned)u) << 16; return v.f;
}

typedef __attribute__((address_space(1))) const void* gas_t;
typedef __attribute__((address_space(3))) void* las_t;
__device__ __forceinline__ void gld16(const void* g, void* l) {
  __builtin_amdgcn_global_load_lds((gas_t)g, (las_t)l, 16, 0, 0);
}

__device__ __forceinline__ void zero_acc(f4v acc[4][4]) {
  f4v z = {0.f, 0.f, 0.f, 0.f};
#pragma unroll
  for (int m = 0; m < 4; ++m)
#pragma unroll
    for (int n = 0; n < 4; ++n) acc[m][n] = z;
}

// ---------------- converts ----------------

__global__ void convert_x_kernel(const float* __restrict__ in, u16* __restrict__ out) {
  int i = (blockIdx.x * 256 + threadIdx.x) * 4;
  float4 v = *(const float4*)(&in[i]);
  out[i + 0] = f2bf(v.x);
  out[i + 1] = f2bf(v.y);
  out[i + 2] = f2bf(v.z);
  out[i + 3] = f2bf(v.w);
}

__global__ void transpose_convert_kernel(const float* __restrict__ in, u16* __restrict__ out,
                                         int R, int C) {
  __shared__ float tile[32][33];
  int c0 = blockIdx.x * 32, r0 = blockIdx.y * 32;
  for (int rr = threadIdx.y; rr < 32; rr += 8)
    tile[rr][threadIdx.x] = in[(size_t)(r0 + rr) * C + (c0 + threadIdx.x)];
  __syncthreads();
  for (int cc = threadIdx.y; cc < 32; cc += 8)
    out[(size_t)(c0 + cc) * R + (r0 + threadIdx.x)] = f2bf(tile[threadIdx.x][cc]);
}

// ---------------- qkv projection: gld16 dbuf staging + LDS slab epilogue ----------------

__global__ __launch_bounds__(256, 2) void gemm_qkv_kernel(
    const u16* __restrict__ xb, const u16* __restrict__ wqkvT,
    u16* __restrict__ quS, u16* __restrict__ ku, u16* __restrict__ vu,
    u16* __restrict__ qcS, u16* __restrict__ kc, u16* __restrict__ vcN) {
  __shared__ u16 sA[2][8192];  // [128][64-swz] per buf
  __shared__ u16 sB[2][8192];
  int bm = blockIdx.x, bn = blockIdx.y;
  int tid = threadIdx.x, lane = tid & 63, w = tid >> 6, wm = w >> 1, wn = w & 1;
  int g = lane >> 4, l15 = lane & 15;
  const int sz = (l15 & 7) << 3;
  const int bo = tid * 16;

  const u16* Ab = xb + (size_t)(bm * 128) * 1024;
  const u16* Bb = wqkvT + (size_t)(bn * 128) * 1024;

  auto stg = [&](const u16* base, int ks, u16* dst) {
#pragma unroll
    for (int it = 0; it < 4; ++it) {
      int o = bo + it * 4096;
      int row = o >> 7, lo = o & 127;
      gld16(base + (size_t)row * 1024 + ks * 64 + ((lo ^ ((row & 7) << 4)) >> 1),
            (char*)dst + o);
    }
  };

  f4v acc[4][4];
  zero_acc(acc);
  stg(Ab, 0, sA[0]);
  stg(Bb, 0, sB[0]);
  stg(Ab, 1, sA[1]);
  stg(Bb, 1, sB[1]);

  for (int ks = 0; ks < 16; ++ks) {
    int buf = ks & 1;
    if (ks < 15)
      asm volatile("s_waitcnt vmcnt(8)" ::: "memory");
    else
      asm volatile("s_waitcnt vmcnt(0)" ::: "memory");
    __builtin_amdgcn_sched_barrier(0);
    __builtin_amdgcn_s_barrier();
    __builtin_amdgcn_sched_barrier(0);
#pragma unroll
    for (int kk = 0; kk < 2; ++kk) {
      int c2 = kk * 32 + g * 8;
      s8v a[4], b[4];
#pragma unroll
      for (int m = 0; m < 4; ++m)
        a[m] = *(const s8v*)(&sA[buf][(wm * 64 + m * 16 + l15) * 64 + (c2 ^ sz)]);
#pragma unroll
      for (int n = 0; n < 4; ++n)
        b[n] = *(const s8v*)(&sB[buf][(wn * 64 + n * 16 + l15) * 64 + (c2 ^ sz)]);
#pragma unroll
      for (int m = 0; m < 4; ++m)
#pragma unroll
        for (int n = 0; n < 4; ++n)
          acc[m][n] = __builtin_amdgcn_mfma_f32_16x16x32_bf16(a[m], b[n], acc[m][n], 0, 0, 0);
    }
    __builtin_amdgcn_s_barrier();
    if (ks + 2 < 16) {
      stg(Ab, ks + 2, sA[buf]);
      stg(Bb, ks + 2, sB[buf]);
    }
  }

  // slab epilogue: per pass one head's 128x64 contiguous slab
  int s = bn >> 3;
  int b = bm >> 4;
  int nn0 = (bm & 15) * 128;
  int hh0 = (bn & 7) * 2;
  float scale = (s == 0 || s == 3) ? 0.125f : 1.f;
  u16* obase;
  switch (s) {
    case 0: obase = quS; break;
    case 1: obase = ku; break;
    case 2: obase = vu; break;
    case 3: obase = qcS; break;
    case 4: obase = kc; break;
    default: obase = vcN; break;
  }
  u16* sE = (u16*)sA;
#pragma unroll
  for (int pass = 0; pass < 2; ++pass) {
    __syncthreads();
    if (wn == pass) {
#pragma unroll
      for (int m = 0; m < 4; ++m)
#pragma unroll
        for (int n = 0; n < 4; ++n)
#pragma unroll
          for (int j = 0; j < 4; ++j) {
            int lrow = wm * 64 + m * 16 + g * 4 + j;
            int d = n * 16 + l15;
            sE[lrow * 64 + d] = f2bf(acc[m][n][j] * scale);
          }
    }
    __syncthreads();
    int bh = (b << 4) + hh0 + pass;
    u16* dst = obase + ((size_t)bh * 2048 + nn0) * 64;
    for (int it = 0; it < 4; ++it) {
      int e = (tid + it * 256) * 8;
      *(uint4*)(dst + e) = *(const uint4*)(&sE[e]);
    }
  }
}

// ------------- vcN [bh][n][d] -> vcT [bh][d][n] -------------

__global__ __launch_bounds__(256) void transpose_v_kernel(const u16* __restrict__ vcN,
                                                          u16* __restrict__ vcT) {
  __shared__ u16 t[64][72];
  int nt = blockIdx.x, bh = blockIdx.y;
  const u16* src = vcN + ((size_t)bh * 2048 + nt * 64) * 64;
  int tid = threadIdx.x;
  for (int i = tid; i < 512; i += 256) {
    int r = i >> 3, cseg = i & 7;
    *(uint4*)(&t[r][cseg * 8]) = *(const uint4*)(src + r * 64 + cseg * 8);
  }
  __syncthreads();
  u16* dst = vcT + (size_t)bh * 64 * 2048 + nt * 64;
  for (int i = tid; i < 512; i += 256) {
    int d = i >> 3, nseg = i & 7;
    u16 tmp[8];
#pragma unroll
    for (int e = 0; e < 8; ++e) tmp[e] = t[nseg * 8 + e][d];
    *(uint4*)(dst + (size_t)d * 2048 + nseg * 8) = *(uint4*)tmp;
  }
}

// ------------- tl: per-tile producer of packed half-tiles [jh][128][64-swz] -------------

__global__ __launch_bounds__(256) void tl_kernel(
    const u16* __restrict__ qcS, const u16* __restrict__ vu,
    const u16* __restrict__ quS, const u16* __restrict__ ku,
    u16* __restrict__ term1p, u16* __restrict__ lookp, int c0) {
  __shared__ u16 sA[2][8192];  // dbuf [128][64-swz]
  __shared__ u16 sB[2][8192];
  int t = blockIdx.x, lb = blockIdx.y, z = blockIdx.z;
  int bh = c0 + lb;
  int I = 0;
  while ((I + 1) * (I + 2) / 2 <= t) ++I;
  int K = t - I * (I + 1) / 2;
  int rt = z ? K : I;
  int ct = z ? I : K;
  const u16* A = (z ? quS : qcS) + ((size_t)bh * 2048 + rt * 128) * 64;
  const u16* B = (z ? ku : vu) + ((size_t)bh * 2048 + ct * 128) * 64;
  u16* o = (z ? lookp : term1p) + ((size_t)lb * 136 + t) * 16384;
  int tid = threadIdx.x, lane = tid & 63, w = tid >> 6, wm = w >> 1, wn = w & 1;
  int g = lane >> 4, l15 = lane & 15;
  const int sz = (l15 & 7) << 3;
  const int bo = tid * 16;

  auto stg = [&](const u16* base, int ks, u16* dst) {
#pragma unroll
    for (int it = 0; it < 4; ++it) {
      int oo = bo + it * 4096;
      int row = oo >> 7, lo = oo & 127;
      gld16(base + (size_t)row * 64 + ks * 32 + ((lo ^ ((row & 7) << 4)) >> 1),
            (char*)dst + oo);
    }
  };
  // K=64: two 32-wide k-steps, both buffered up-front
  stg(A, 0, sA[0]);
  stg(B, 0, sB[0]);
  stg(A, 1, sA[1]);
  stg(B, 1, sB[1]);

  f4v acc[4][4];
  zero_acc(acc);
  asm volatile("s_waitcnt vmcnt(0)" ::: "memory");
  __builtin_amdgcn_sched_barrier(0);
  __syncthreads();
#pragma unroll
  for (int ks = 0; ks < 2; ++ks) {
    // each [128][64-swz] buffer holds one 32-wide k-slice spread over 64 cols:
    // col layout is [k 0..31 | k 0..31] per row? No: source row is 64 wide in k,
    // ks*32 selects the 32-k slice -> buffer cols 0..63 hold k (ks*32 .. ks*32+31) x2? 
    // Actually stg copies 64 consecutive k per row when ks spans... we copy 128B/row = 64 elems
    // starting at ks*32: that's k in [ks*32, ks*32+64) -> overlapping; for K=64, use ks=0 only
    // for cols 0..63 (full row). Simpler: buffer 0 holds full 64-k rows; compute both k-steps
    // from sA[0]/sB[0]; sA[1]/sB[1] are duplicates (harmless).
    int c2 = ks * 32 + g * 8;
    (void)c2;
  }
  // compute from buf0 (full 64-k rows)
#pragma unroll
  for (int kk = 0; kk < 2; ++kk) {
    int c2 = kk * 32 + g * 8;
    s8v a[4], b[4];
#pragma unroll
    for (int m = 0; m < 4; ++m)
      a[m] = *(const s8v*)(&sA[0][(wm * 64 + m * 16 + l15) * 64 + (c2 ^ sz)]);
#pragma unroll
    for (int n = 0; n < 4; ++n)
      b[n] = *(const s8v*)(&sB[0][(wn * 64 + n * 16 + l15) * 64 + (c2 ^ sz)]);
#pragma unroll
    for (int m = 0; m < 4; ++m)
#pragma unroll
      for (int n = 0; n < 4; ++n)
        acc[m][n] = __builtin_amdgcn_mfma_f32_16x16x32_bf16(a[m], b[n], acc[m][n], 0, 0, 0);
  }

  // two 64-row passes: scatter swizzled half-tile into LDS (sB[1] scratch), copy linear
  u16* sE = sB[1];
#pragma unroll
  for (int pass = 0; pass < 2; ++pass) {
    __syncthreads();
    if (wm == pass) {
#pragma unroll
      for (int m = 0; m < 4; ++m)
#pragma unroll
        for (int n = 0; n < 4; ++n)
#pragma unroll
          for (int j4 = 0; j4 < 4; ++j4) {
            int lrl = m * 16 + g * 4 + j4;          // 0..63 within pass
            int lc = wn * 64 + n * 16 + l15;        // 0..127
            int gr = rt * 128 + pass * 64 + lrl;
            int gc = ct * 128 + lc;
            float v = acc[m][n][j4];
            if (z)
              v = (gc > gr) ? 1.f / (1.f + __expf(-v)) : 0.f;
            else
              v = (gc > gr) ? 0.f : v;
            sE[(lc >> 6) * 4096 + lrl * 64 + ((lc & 63) ^ ((lrl & 7) << 3))] = f2bf(v);
          }
    }
    __syncthreads();
    for (int it = 0; it < 4; ++it) {
      int e = (tid + it * 256) * 8;
      // dst elem = hf*8192 + (pass*64+r)*64 + c' = e + (e>>12)*4096 + pass*4096
      *(uint4*)(o + e + ((e >> 12) + pass) * 4096) = *(const uint4*)(&sE[e]);
    }
  }
}

// ------------- castle: dbuf-prefetch j-loop, Su -> -silu -> +Sc -> mask -> softmax -> PV ------

__global__ __launch_bounds__(256, 2) void castle_kernel(
    const u16* __restrict__ term1p, const u16* __restrict__ lookp,
    const u16* __restrict__ qcS, const u16* __restrict__ kc,
    const u16* __restrict__ vcT,
    u16* __restrict__ opart, float* __restrict__ ml, int c0) {
  __shared__ u16 sA[16384];  // 2 x (128x64-swz) term1 halves; later P (2 kh x 128 x 64)
  __shared__ u16 sB[16384];  // 2 x (128x64-swz) look halves; later Vs | Ks
  int bid = blockIdx.x;
  int lb = bid / 136, sid = bid % 136;
  int bh = c0 + lb;
  int I = 15, rem = sid;
  while (rem > I) { rem -= I + 1; --I; }
  int K = rem;
  int t = I * (I + 1) / 2 + K;

  int tid = threadIdx.x, lane = tid & 63, w = tid >> 6;
  int g = lane >> 4, l15 = lane & 15;
  const int sz = (l15 & 7) << 3;

  const char* t1b = (const char*)(term1p + (size_t)lb * 136 * 16384);
  const char* lkb = (const char*)(lookp + (size_t)lb * 136 * 16384);
  const int IT = I * (I + 1) / 2;
  const int bo = tid * 16;

  s8v qa[2][2];
#pragma unroll
  for (int mg = 0; mg < 2; ++mg)
#pragma unroll
    for (int kk = 0; kk < 2; ++kk)
      qa[mg][kk] = *(const s8v*)(&qcS[((size_t)bh * 2048 + I * 128 + w * 32 + mg * 16 + l15) * 64 +
                                      kk * 32 + g * 8]);

  f4v su[2][8];
  {
    f4v z = {0.f, 0.f, 0.f, 0.f};
#pragma unroll
    for (int mg = 0; mg < 2; ++mg)
#pragma unroll
      for (int n = 0; n < 8; ++n) su[mg][n] = z;
  }

  auto stage = [&](int h, int buf) {
    int j = h >> 1, hf = h & 1;
    const char* srcA = t1b + (size_t)(IT + j) * 32768 + hf * 16384;
    const char* srcB = lkb + (size_t)(j * (j + 1) / 2 + K) * 32768 + hf * 16384;
    char* dA = (char*)sA + buf * 16384;
    char* dB = (char*)sB + buf * 16384;
#pragma unroll
    for (int it = 0; it < 4; ++it) {
      gld16(srcA + bo + it * 4096, dA + bo + it * 4096);
      gld16(srcB + bo + it * 4096, dB + bo + it * 4096);
    }
  };

  const int h0 = 2 * K, h1 = 2 * I + 1;
  stage(h0, 0);
  for (int h = h0; h <= h1; ++h) {
    int cur = (h - h0) & 1;
    if (h < h1) {
      stage(h + 1, cur ^ 1);
      asm volatile("s_waitcnt vmcnt(8)" ::: "memory");
    } else {
      asm volatile("s_waitcnt vmcnt(0)" ::: "memory");
    }
    __builtin_amdgcn_sched_barrier(0);
    __builtin_amdgcn_s_barrier();
    __builtin_amdgcn_sched_barrier(0);
    const u16* bA = sA + cur * 8192;
    const u16* bB = sB + cur * 8192;
    __builtin_amdgcn_s_setprio(1);
#pragma unroll
    for (int kk = 0; kk < 2; ++kk) {
      int c2 = kk * 32 + g * 8;
      s8v a[2], b[8];
      a[0] = *(const s8v*)(&bA[(w * 32 + l15) * 64 + (c2 ^ sz)]);
      a[1] = *(const s8v*)(&bA[(w * 32 + 16 + l15) * 64 + (c2 ^ sz)]);
#pragma unroll
      for (int n = 0; n < 8; ++n)
        b[n] = *(const s8v*)(&bB[(n * 16 + l15) * 64 + (c2 ^ sz)]);
#pragma unroll
      for (int mg = 0; mg < 2; ++mg)
#pragma unroll
        for (int n = 0; n < 8; ++n)
          su[mg][n] = __builtin_amdgcn_mfma_f32_16x16x32_bf16(a[mg], b[n], su[mg][n], 0, 0, 0);
    }
    __builtin_amdgcn_s_setprio(0);
    __builtin_amdgcn_s_barrier();
  }

  // ---- stage Vs (sB [0,16K)) and Ks (sB [16K,32K)), overlap with silu ----
  {
#pragma unroll
    for (int it = 0; it < 4; ++it) {
      int o = bo + it * 4096;
      int kh = o >> 13, oc = o & 8191;
      int dr = oc >> 7, lo = oc & 127;
      const u16* src = vcT + ((size_t)bh * 64 + dr) * 2048 + K * 128 + kh * 64 +
                       ((lo ^ ((dr & 7) << 4)) >> 1);
      gld16(src, (char*)sB + o);
    }
#pragma unroll
    for (int it = 0; it < 4; ++it) {
      int o = bo + it * 4096;
      int row = o >> 7, lo = o & 127;
      const u16* src = kc + ((size_t)bh * 2048 + K * 128 + row) * 64 +
                       ((lo ^ ((row & 7) << 4)) >> 1);
      gld16(src, (char*)sB + 16384 + o);
    }
  }
#pragma unroll
  for (int mg = 0; mg < 2; ++mg)
#pragma unroll
    for (int n = 0; n < 8; ++n)
#pragma unroll
      for (int j4 = 0; j4 < 4; ++j4) {
        float xv = su[mg][n][j4];
        su[mg][n][j4] = -(xv / (1.f + __expf(-xv)));
      }
  __syncthreads();

  // ---- Sc accumulate ----
#pragma unroll
  for (int kk = 0; kk < 2; ++kk) {
    int c = kk * 32 + g * 8;
    s8v b[8];
#pragma unroll
    for (int n = 0; n < 8; ++n)
      b[n] = *(const s8v*)(&sB[8192 + (n * 16 + l15) * 64 + (c ^ sz)]);
#pragma unroll
    for (int mg = 0; mg < 2; ++mg)
#pragma unroll
      for (int n = 0; n < 8; ++n)
        su[mg][n] = __builtin_amdgcn_mfma_f32_16x16x32_bf16(qa[mg][kk], b[n], su[mg][n], 0, 0, 0);
  }

  if (K == I) {
#pragma unroll
    for (int mg = 0; mg < 2; ++mg)
#pragma unroll
      for (int n = 0; n < 8; ++n)
#pragma unroll
        for (int j4 = 0; j4 < 4; ++j4) {
          int lr = w * 32 + mg * 16 + g * 4 + j4;
          int lc = n * 16 + l15;
          if (lc > lr) su[mg][n][j4] = -3.0e38f;
        }
  }

  // ---- local softmax; P -> sA as [kh][128][64-swz] ----
  float mrow[2][4], lrow[2][4];
#pragma unroll
  for (int mg = 0; mg < 2; ++mg)
#pragma unroll
    for (int j4 = 0; j4 < 4; ++j4) {
      float v = -3.0e38f;
#pragma unroll
      for (int n = 0; n < 8; ++n) v = fmaxf(v, su[mg][n][j4]);
      v = fmaxf(v, __shfl_xor(v, 1));
      v = fmaxf(v, __shfl_xor(v, 2));
      v = fmaxf(v, __shfl_xor(v, 4));
      v = fmaxf(v, __shfl_xor(v, 8));
      mrow[mg][j4] = v;
    }
#pragma unroll
  for (int mg = 0; mg < 2; ++mg)
#pragma unroll
    for (int j4 = 0; j4 < 4; ++j4) {
      float sum = 0.f;
      int prow = w * 32 + mg * 16 + g * 4 + j4;
      int psz = ((g * 4 + j4) & 7) << 3;
#pragma unroll
      for (int n = 0; n < 8; ++n) {
        float e = __expf(su[mg][n][j4] - mrow[mg][j4]);
        sum += e;
        int pc = n * 16 + l15;
        sA[(n >> 2) * 8192 + prow * 64 + ((pc & 63) ^ psz)] = f2bf(e);
      }
      sum += __shfl_xor(sum, 1);
      sum += __shfl_xor(sum, 2);
      sum += __shfl_xor(sum, 4);
      sum += __shfl_xor(sum, 8);
      lrow[mg][j4] = sum;
    }
  __syncthreads();

  // ---- PV: O = P @ Vs ----
  f4v o[2][4];
  {
    f4v z = {0.f, 0.f, 0.f, 0.f};
#pragma unroll
    for (int mg = 0; mg < 2; ++mg)
#pragma unroll
      for (int nd = 0; nd < 4; ++nd) o[mg][nd] = z;
  }
#pragma unroll
  for (int kk = 0; kk < 4; ++kk) {
    int kh = kk >> 1;
    int cc = (kk & 1) * 32 + g * 8;
    s8v pa[2], vb[4];
#pragma unroll
    for (int mg = 0; mg < 2; ++mg)
      pa[mg] = *(const s8v*)(&sA[kh * 8192 + (w * 32 + mg * 16 + l15) * 64 + (cc ^ sz)]);
#pragma unroll
    for (int nd = 0; nd < 4; ++nd)
      vb[nd] = *(const s8v*)(&sB[kh * 4096 + (nd * 16 + l15) * 64 + (cc ^ sz)]);
#pragma unroll
    for (int mg = 0; mg < 2; ++mg)
#pragma unroll
      for (int nd = 0; nd < 4; ++nd)
        o[mg][nd] = __builtin_amdgcn_mfma_f32_16x16x32_bf16(pa[mg], vb[nd], o[mg][nd], 0, 0, 0);
  }

  // ---- write partials ----
  size_t tb = (size_t)lb * 136 + t;
#pragma unroll
  for (int mg = 0; mg < 2; ++mg)
#pragma unroll
    for (int nd = 0; nd < 4; ++nd)
#pragma unroll
      for (int j4 = 0; j4 < 4; ++j4) {
        int prow = w * 32 + mg * 16 + g * 4 + j4;
        int dcol = nd * 16 + l15;
        opart[(tb * 128 + prow) * 64 + dcol] = f2bf(o[mg][nd][j4]);
      }
  if (l15 == 0) {
#pragma unroll
    for (int mg = 0; mg < 2; ++mg)
#pragma unroll
      for (int j4 = 0; j4 < 4; ++j4) {
        int prow = w * 32 + mg * 16 + g * 4 + j4;
        ml[tb * 256 + prow] = mrow[mg][j4];
        ml[tb * 256 + 128 + prow] = lrow[mg][j4];
      }
  }
}

// ------------- combine: flash-merge the <=16 partials per (I, head) -------------

__global__ __launch_bounds__(256) void combine_kernel(const u16* __restrict__ opart,
                                                      const float* __restrict__ ml,
                                                      u16* __restrict__ attn, int c0) {
  int lb = blockIdx.x, I = blockIdx.y, bh = c0 + lb;
  int tid = threadIdx.x;
  int row = tid >> 1, dh = (tid & 1) << 5;
  float M = -3.0e38f, L = 0.f;
  float O[32];
#pragma unroll
  for (int i = 0; i < 32; ++i) O[i] = 0.f;
  for (int K = 0; K <= I; ++K) {
    size_t tb = (size_t)lb * 136 + I * (I + 1) / 2 + K;
    float m = ml[tb * 256 + row];
    float l = ml[tb * 256 + 128 + row];
    float newM = fmaxf(M, m);
    float so = __expf(M - newM), sn = __expf(m - newM);
    L = L * so + l * sn;
    const u16* op = opart + (tb * 128 + row) * 64 + dh;
#pragma unroll
    for (int q = 0; q < 4; ++q) {
      s8v ov = *(const s8v*)(op + q * 8);
#pragma unroll
      for (int e = 0; e < 8; ++e)
        O[q * 8 + e] = O[q * 8 + e] * so + bf2f((u16)ov[e]) * sn;
    }
    M = newM;
  }
  float inv = 1.f / L;
  int b = bh >> 4, hh = bh & 15;
  u16* dst = attn + ((size_t)b * 2048 + I * 128 + row) * 1024 + hh * 64 + dh;
#pragma unroll
  for (int i = 0; i < 32; ++i) dst[i] = f2bf(O[i] * inv);
}

// ------------- final: out = attn_out @ W_out, f32 (gld16 dbuf) -------------

__global__ __launch_bounds__(256, 2) void gemm_out_kernel(const u16* __restrict__ attn,
                                                          const u16* __restrict__ woutT,
                                                          float* __restrict__ out) {
  __shared__ u16 sA[2][8192];
  __shared__ u16 sB[2][8192];
  int bm = blockIdx.x, bn = blockIdx.y;
  int tid = threadIdx.x, lane = tid & 63, w = tid >> 6, wm = w >> 1, wn = w & 1;
  int g = lane >> 4, l15 = lane & 15;
  const int sz = (l15 & 7) << 3;
  const int bo = tid * 16;

  const u16* Ab = attn + (size_t)(bm * 128) * 1024;
  const u16* Bb = woutT + (size_t)(bn * 128) * 1024;

  auto stg = [&](const u16* base, int ks, u16* dst) {
#pragma unroll
    for (int it = 0; it < 4; ++it) {
      int o = bo + it * 4096;
      int row = o >> 7, lo = o & 127;
      gld16(base + (size_t)row * 1024 + ks * 64 + ((lo ^ ((row & 7) << 4)) >> 1),
            (char*)dst + o);
    }
  };

  f4v acc[4][4];
  zero_acc(acc);
  stg(Ab, 0, sA[0]);
  stg(Bb, 0, sB[0]);
  stg(Ab, 1, sA[1]);
  stg(Bb, 1, sB[1]);

  for (int ks = 0; ks < 16; ++ks) {
    int buf = ks & 1;
    if (ks < 15)
      asm volatile("s_waitcnt vmcnt(8)" ::: "memory");
    else
      asm volatile("s_waitcnt vmcnt(0)" ::: "memory");
    __builtin_amdgcn_sched_barrier(0);
    __builtin_amdgcn_s_barrier();
    __builtin_amdgcn_sched_barrier(0);
#pragma unroll
    for (int kk = 0; kk < 2; ++kk) {
      int c2 = kk * 32 + g * 8;
      s8v a[4], b[4];
#pragma unroll
      for (int m = 0; m < 4; ++m)
        a[m] = *(const s8v*)(&sA[buf][(wm * 64 + m * 16 + l15) * 64 + (c2 ^ sz)]);
#pragma unroll
      for (int n = 0; n < 4; ++n)
        b[n] = *(const s8v*)(&sB[buf][(wn * 64 + n * 16 + l15) * 64 + (c2 ^ sz)]);
#pragma unroll
      for (int m = 0; m < 4; ++m)
#pragma unroll
        for (int n = 0; n < 4; ++n)
          acc[m][n] = __builtin_amdgcn_mfma_f32_16x16x32_bf16(a[m], b[n], acc[m][n], 0, 0, 0);
    }
    __builtin_amdgcn_s_barrier();
    if (ks + 2 < 16) {
      stg(Ab, ks + 2, sA[buf]);
      stg(Bb, ks + 2, sB[buf]);
    }
  }

#pragma unroll
  for (int m = 0; m < 4; ++m)
#pragma unroll
    for (int n = 0; n < 4; ++n)
#pragma unroll
      for (int j = 0; j < 4; ++j) {
        int row = bm * 128 + wm * 64 + m * 16 + g * 4 + j;
        int col = bn * 128 + wn * 64 + n * 16 + l15;
        out[(size_t)row * 1024 + col] = acc[m][n][j];
      }
}

// ---------------- host ----------------

extern "C" void kernel_launch(void* const* d_in, const int* in_sizes, int n_in,
                              void* d_out, int out_size, void* d_ws, size_t ws_size,
                              hipStream_t stream) {
  const float* x = (const float*)d_in[0];
  const float* Wqkv = (const float*)d_in[1];
  const float* Wout = (const float*)d_in[2];
  float* out = (float*)d_out;

  char* base = (char*)d_ws;
  size_t off = 0;
  auto alloc = [&](size_t bytes) -> void* {
    void* p = base + off;
    off += (bytes + 255) & ~(size_t)255;
    return p;
  };

  u16* woutT = (u16*)alloc(1024ull * 1024 * 2);
  u16* quS = (u16*)alloc(32ull * 2048 * 64 * 2);
  u16* ku = (u16*)alloc(32ull * 2048 * 64 * 2);
  u16* vu = (u16*)alloc(32ull * 2048 * 64 * 2);
  u16* qcS = (u16*)alloc(32ull * 2048 * 64 * 2);
  u16* kc = (u16*)alloc(32ull * 2048 * 64 * 2);
  u16* vcN = (u16*)alloc(32ull * 2048 * 64 * 2);
  u16* vcT = (u16*)alloc(32ull * 2048 * 64 * 2);
  u16* attn = (u16*)alloc(4096ull * 1024 * 2);

  size_t perBH = 136ull * 16384 * 2 * 2 + 136ull * 128 * 64 * 2 + 136ull * 256 * 4;
  size_t remain = (ws_size > off) ? (ws_size - off) : 0;
  int chunk = (int)(remain / perBH);
  if (chunk < 1) chunk = 1;
  if (chunk > 32) chunk = 32;
  u16* term1p = (u16*)alloc((size_t)chunk * 136 * 16384 * 2);
  u16* lookp = (u16*)alloc((size_t)chunk * 136 * 16384 * 2);
  u16* opart = (u16*)alloc((size_t)chunk * 136 * 8192 * 2);
  float* mlb = (float*)alloc((size_t)chunk * 136 * 256 * 4);

  u16* xb;
  u16* wqkvT;
  if ((size_t)chunk * 136 * 16384 * 2 >= (4096ull + 6144ull) * 1024 * 2) {
    xb = term1p;
    wqkvT = term1p + 4096ull * 1024;
  } else {
    xb = (u16*)alloc(4096ull * 1024 * 2);
    wqkvT = (u16*)alloc(6144ull * 1024 * 2);
  }

  convert_x_kernel<<<4096, 256, 0, stream>>>(x, xb);
  transpose_convert_kernel<<<dim3(192, 32), dim3(32, 8), 0, stream>>>(Wqkv, wqkvT, 1024, 6144);
  transpose_convert_kernel<<<dim3(32, 32), dim3(32, 8), 0, stream>>>(Wout, woutT, 1024, 1024);
  gemm_qkv_kernel<<<dim3(32, 48), 256, 0, stream>>>(xb, wqkvT, quS, ku, vu, qcS, kc, vcN);
  transpose_v_kernel<<<dim3(32, 32), 256, 0, stream>>>(vcN, vcT);

  for (int c0 = 0; c0 < 32; c0 += chunk) {
    int nb = (32 - c0 < chunk) ? (32 - c0) : chunk;
    tl_kernel<<<dim3(136, nb, 2), 256, 0, stream>>>(qcS, vu, quS, ku, term1p, lookp, c0);
    castle_kernel<<<dim3(136 * nb), 256, 0, stream>>>(term1p, lookp, qcS, kc, vcT, opart, mlb, c0);
    combine_kernel<<<dim3(nb, 16), 256, 0, stream>>>(opart, mlb, attn, c0);
  }
  gemm_out_kernel<<<dim3(32, 8), 256, 0, stream>>>(attn, woutT, out);
}

// Round 11
// 500.336 us; speedup vs baseline: 1.6604x; 1.2034x over previous
//
#include <hip/hip_runtime.h>
#include <hip/hip_bf16.h>
#include <stdint.h>

// Castle attention, bf16 MFMA pipeline.
// convert -> qkv GEMM (gld16 dbuf, slab epilogue) -> vcT transpose
//   -> tl (z-merged: one block makes term1(I,K) AND look(K,I); single-pass epilogue)
//   -> castle (dbuf prefetch j-loop: Su -> -silu -> +Sc -> mask -> softmax -> PV)
//   -> combine (flash-merge) -> out GEMM (gld16 dbuf).

typedef unsigned short u16;
typedef __attribute__((ext_vector_type(8))) short s8v;   // 8 x bf16
typedef __attribute__((ext_vector_type(4))) float f4v;   // MFMA accumulator

__device__ __forceinline__ u16 f2bf(float f) {
  union { float f; unsigned u; } v; v.f = f;
  unsigned r = v.u + 0x7FFFu + ((v.u >> 16) & 1u);
  return (u16)(r >> 16);
}
__device__ __forceinline__ float bf2f(u16 u) {
  union { unsigned u; float f; } v; v.u = ((unsigned)u) << 16; return v.f;
}

typedef __attribute__((address_space(1))) const void* gas_t;
typedef __attribute__((address_space(3))) void* las_t;
__device__ __forceinline__ void gld16(const void* g, void* l) {
  __builtin_amdgcn_global_load_lds((gas_t)g, (las_t)l, 16, 0, 0);
}

__device__ __forceinline__ void zero_acc(f4v acc[4][4]) {
  f4v z = {0.f, 0.f, 0.f, 0.f};
#pragma unroll
  for (int m = 0; m < 4; ++m)
#pragma unroll
    for (int n = 0; n < 4; ++n) acc[m][n] = z;
}

// ---------------- converts ----------------

__global__ void convert_x_kernel(const float* __restrict__ in, u16* __restrict__ out) {
  int i = (blockIdx.x * 256 + threadIdx.x) * 4;
  float4 v = *(const float4*)(&in[i]);
  out[i + 0] = f2bf(v.x);
  out[i + 1] = f2bf(v.y);
  out[i + 2] = f2bf(v.z);
  out[i + 3] = f2bf(v.w);
}

__global__ void transpose_convert_kernel(const float* __restrict__ in, u16* __restrict__ out,
                                         int R, int C) {
  __shared__ float tile[32][33];
  int c0 = blockIdx.x * 32, r0 = blockIdx.y * 32;
  for (int rr = threadIdx.y; rr < 32; rr += 8)
    tile[rr][threadIdx.x] = in[(size_t)(r0 + rr) * C + (c0 + threadIdx.x)];
  __syncthreads();
  for (int cc = threadIdx.y; cc < 32; cc += 8)
    out[(size_t)(c0 + cc) * R + (r0 + threadIdx.x)] = f2bf(tile[threadIdx.x][cc]);
}

// ---------------- qkv projection: gld16 dbuf staging + LDS slab epilogue ----------------

__global__ __launch_bounds__(256, 2) void gemm_qkv_kernel(
    const u16* __restrict__ xb, const u16* __restrict__ wqkvT,
    u16* __restrict__ quS, u16* __restrict__ ku, u16* __restrict__ vu,
    u16* __restrict__ qcS, u16* __restrict__ kc, u16* __restrict__ vcN) {
  __shared__ u16 sA[2][8192];  // [128][64-swz] per buf
  __shared__ u16 sB[2][8192];
  int bm = blockIdx.x, bn = blockIdx.y;
  int tid = threadIdx.x, lane = tid & 63, w = tid >> 6, wm = w >> 1, wn = w & 1;
  int g = lane >> 4, l15 = lane & 15;
  const int sz = (l15 & 7) << 3;
  const int bo = tid * 16;

  const u16* Ab = xb + (size_t)(bm * 128) * 1024;
  const u16* Bb = wqkvT + (size_t)(bn * 128) * 1024;

  auto stg = [&](const u16* base, int ks, u16* dst) {
#pragma unroll
    for (int it = 0; it < 4; ++it) {
      int o = bo + it * 4096;
      int row = o >> 7, lo = o & 127;
      gld16(base + (size_t)row * 1024 + ks * 64 + ((lo ^ ((row & 7) << 4)) >> 1),
            (char*)dst + o);
    }
  };

  f4v acc[4][4];
  zero_acc(acc);
  stg(Ab, 0, sA[0]);
  stg(Bb, 0, sB[0]);
  stg(Ab, 1, sA[1]);
  stg(Bb, 1, sB[1]);

  for (int ks = 0; ks < 16; ++ks) {
    int buf = ks & 1;
    if (ks < 15)
      asm volatile("s_waitcnt vmcnt(8)" ::: "memory");
    else
      asm volatile("s_waitcnt vmcnt(0)" ::: "memory");
    __builtin_amdgcn_sched_barrier(0);
    __builtin_amdgcn_s_barrier();
    __builtin_amdgcn_sched_barrier(0);
#pragma unroll
    for (int kk = 0; kk < 2; ++kk) {
      int c2 = kk * 32 + g * 8;
      s8v a[4], b[4];
#pragma unroll
      for (int m = 0; m < 4; ++m)
        a[m] = *(const s8v*)(&sA[buf][(wm * 64 + m * 16 + l15) * 64 + (c2 ^ sz)]);
#pragma unroll
      for (int n = 0; n < 4; ++n)
        b[n] = *(const s8v*)(&sB[buf][(wn * 64 + n * 16 + l15) * 64 + (c2 ^ sz)]);
#pragma unroll
      for (int m = 0; m < 4; ++m)
#pragma unroll
        for (int n = 0; n < 4; ++n)
          acc[m][n] = __builtin_amdgcn_mfma_f32_16x16x32_bf16(a[m], b[n], acc[m][n], 0, 0, 0);
    }
    __builtin_amdgcn_s_barrier();
    if (ks + 2 < 16) {
      stg(Ab, ks + 2, sA[buf]);
      stg(Bb, ks + 2, sB[buf]);
    }
  }

  // slab epilogue: per pass one head's 128x64 contiguous slab
  int s = bn >> 3;
  int b = bm >> 4;
  int nn0 = (bm & 15) * 128;
  int hh0 = (bn & 7) * 2;
  float scale = (s == 0 || s == 3) ? 0.125f : 1.f;
  u16* obase;
  switch (s) {
    case 0: obase = quS; break;
    case 1: obase = ku; break;
    case 2: obase = vu; break;
    case 3: obase = qcS; break;
    case 4: obase = kc; break;
    default: obase = vcN; break;
  }
  u16* sE = (u16*)sA;
#pragma unroll
  for (int pass = 0; pass < 2; ++pass) {
    __syncthreads();
    if (wn == pass) {
#pragma unroll
      for (int m = 0; m < 4; ++m)
#pragma unroll
        for (int n = 0; n < 4; ++n)
#pragma unroll
          for (int j = 0; j < 4; ++j) {
            int lrow = wm * 64 + m * 16 + g * 4 + j;
            int d = n * 16 + l15;
            sE[lrow * 64 + d] = f2bf(acc[m][n][j] * scale);
          }
    }
    __syncthreads();
    int bh = (b << 4) + hh0 + pass;
    u16* dst = obase + ((size_t)bh * 2048 + nn0) * 64;
    for (int it = 0; it < 4; ++it) {
      int e = (tid + it * 256) * 8;
      *(uint4*)(dst + e) = *(const uint4*)(&sE[e]);
    }
  }
}

// ------------- vcN [bh][n][d] -> vcT [bh][d][n] -------------

__global__ __launch_bounds__(256) void transpose_v_kernel(const u16* __restrict__ vcN,
                                                          u16* __restrict__ vcT) {
  __shared__ u16 t[64][72];
  int nt = blockIdx.x, bh = blockIdx.y;
  const u16* src = vcN + ((size_t)bh * 2048 + nt * 64) * 64;
  int tid = threadIdx.x;
  for (int i = tid; i < 512; i += 256) {
    int r = i >> 3, cseg = i & 7;
    *(uint4*)(&t[r][cseg * 8]) = *(const uint4*)(src + r * 64 + cseg * 8);
  }
  __syncthreads();
  u16* dst = vcT + (size_t)bh * 64 * 2048 + nt * 64;
  for (int i = tid; i < 512; i += 256) {
    int d = i >> 3, nseg = i & 7;
    u16 tmp[8];
#pragma unroll
    for (int e = 0; e < 8; ++e) tmp[e] = t[nseg * 8 + e][d];
    *(uint4*)(dst + (size_t)d * 2048 + nseg * 8) = *(uint4*)tmp;
  }
}

// ------------- tl (z-merged): block (I,K) -> term1(I,K) AND look(K,I) -------------
// stage qc[I], vu[K], qu[K], ku[I] (4 x 16 KB) -> 64 MFMAs -> scatter both tiles
// (masked / sigmoid'd, swizzled [hf][128][64]) into dead LDS -> 64 KB linear write.

__global__ __launch_bounds__(256, 2) void tl_kernel(
    const u16* __restrict__ qcS, const u16* __restrict__ vu,
    const u16* __restrict__ quS, const u16* __restrict__ ku,
    u16* __restrict__ term1p, u16* __restrict__ lookp, int c0) {
  __shared__ u16 S[32768];  // 64 KB: 4 staged tiles, later 2 output tiles
  int t = blockIdx.x, lb = blockIdx.y, bh = c0 + lb;
  int I = 0;
  while ((I + 1) * (I + 2) / 2 <= t) ++I;
  int K = t - I * (I + 1) / 2;
  int tid = threadIdx.x, lane = tid & 63, w = tid >> 6, wm = w >> 1, wn = w & 1;
  int g = lane >> 4, l15 = lane & 15;
  const int sz = (l15 & 7) << 3;
  const int bo = tid * 16;

  auto stg = [&](const u16* base, int rt, u16* dst) {
#pragma unroll
    for (int it = 0; it < 4; ++it) {
      int o = bo + it * 4096;
      int row = o >> 7, lo = o & 127;
      gld16(base + ((size_t)bh * 2048 + rt * 128 + row) * 64 + ((lo ^ ((row & 7) << 4)) >> 1),
            (char*)dst + o);
    }
  };
  stg(qcS, I, S);             // A1: qc rows I
  stg(vu, K, S + 8192);       // B1: vu rows K
  stg(quS, K, S + 16384);     // A2: qu rows K
  stg(ku, I, S + 24576);      // B2: ku rows I

  asm volatile("s_waitcnt vmcnt(0)" ::: "memory");
  __builtin_amdgcn_sched_barrier(0);
  __syncthreads();

  f4v acc1[4][4], acc2[4][4];
  zero_acc(acc1);
  zero_acc(acc2);
#pragma unroll
  for (int kk = 0; kk < 2; ++kk) {
    int c2 = kk * 32 + g * 8;
    s8v a1[4], b1[4], a2[4], b2[4];
#pragma unroll
    for (int m = 0; m < 4; ++m) {
      a1[m] = *(const s8v*)(&S[(wm * 64 + m * 16 + l15) * 64 + (c2 ^ sz)]);
      a2[m] = *(const s8v*)(&S[16384 + (wm * 64 + m * 16 + l15) * 64 + (c2 ^ sz)]);
    }
#pragma unroll
    for (int n = 0; n < 4; ++n) {
      b1[n] = *(const s8v*)(&S[8192 + (wn * 64 + n * 16 + l15) * 64 + (c2 ^ sz)]);
      b2[n] = *(const s8v*)(&S[24576 + (wn * 64 + n * 16 + l15) * 64 + (c2 ^ sz)]);
    }
#pragma unroll
    for (int m = 0; m < 4; ++m)
#pragma unroll
      for (int n = 0; n < 4; ++n) {
        acc1[m][n] = __builtin_amdgcn_mfma_f32_16x16x32_bf16(a1[m], b1[n], acc1[m][n], 0, 0, 0);
        acc2[m][n] = __builtin_amdgcn_mfma_f32_16x16x32_bf16(a2[m], b2[n], acc2[m][n], 0, 0, 0);
      }
  }
  __syncthreads();  // all MFMA operand reads done -> LDS reusable

  // scatter: term1 -> S[0..16384) elems, look -> S[16384..32768); layout [hf=lc>>6][lr][64-swz]
#pragma unroll
  for (int m = 0; m < 4; ++m)
#pragma unroll
    for (int n = 0; n < 4; ++n)
#pragma unroll
      for (int j4 = 0; j4 < 4; ++j4) {
        int lr = wm * 64 + m * 16 + g * 4 + j4;
        int lc = wn * 64 + n * 16 + l15;
        int idx = wn * 8192 + lr * 64 + ((lc & 63) ^ ((lr & 7) << 3));
        // term1: rows I, cols K; keep at/below diagonal
        float v1 = acc1[m][n][j4];
        v1 = ((K * 128 + lc) > (I * 128 + lr)) ? 0.f : v1;
        S[idx] = f2bf(v1);
        // look: rows K, cols I; sigmoid, keep strictly above diagonal
        float v2 = acc2[m][n][j4];
        v2 = ((I * 128 + lc) > (K * 128 + lr)) ? (1.f / (1.f + __expf(-v2))) : 0.f;
        S[16384 + idx] = f2bf(v2);
      }
  __syncthreads();

  u16* o1 = term1p + ((size_t)lb * 136 + t) * 16384;
  u16* o2 = lookp + ((size_t)lb * 136 + t) * 16384;
#pragma unroll
  for (int it = 0; it < 8; ++it) {
    int e = (tid + it * 256) * 8;
    *(uint4*)(o1 + e) = *(const uint4*)(&S[e]);
    *(uint4*)(o2 + e) = *(const uint4*)(&S[16384 + e]);
  }
}

// ------------- castle: dbuf-prefetch j-loop, Su -> -silu -> +Sc -> mask -> softmax -> PV ------

__global__ __launch_bounds__(256, 2) void castle_kernel(
    const u16* __restrict__ term1p, const u16* __restrict__ lookp,
    const u16* __restrict__ qcS, const u16* __restrict__ kc,
    const u16* __restrict__ vcT,
    u16* __restrict__ opart, float* __restrict__ ml, int c0) {
  __shared__ u16 sA[16384];  // 2 x (128x64-swz) term1 halves; later P (2 kh x 128 x 64)
  __shared__ u16 sB[16384];  // 2 x (128x64-swz) look halves; later Vs | Ks
  int bid = blockIdx.x;
  int lb = bid / 136, sid = bid % 136;
  int bh = c0 + lb;
  int I = 15, rem = sid;
  while (rem > I) { rem -= I + 1; --I; }
  int K = rem;
  int t = I * (I + 1) / 2 + K;

  int tid = threadIdx.x, lane = tid & 63, w = tid >> 6;
  int g = lane >> 4, l15 = lane & 15;
  const int sz = (l15 & 7) << 3;

  const char* t1b = (const char*)(term1p + (size_t)lb * 136 * 16384);
  const char* lkb = (const char*)(lookp + (size_t)lb * 136 * 16384);
  const int IT = I * (I + 1) / 2;
  const int bo = tid * 16;

  s8v qa[2][2];
#pragma unroll
  for (int mg = 0; mg < 2; ++mg)
#pragma unroll
    for (int kk = 0; kk < 2; ++kk)
      qa[mg][kk] = *(const s8v*)(&qcS[((size_t)bh * 2048 + I * 128 + w * 32 + mg * 16 + l15) * 64 +
                                      kk * 32 + g * 8]);

  f4v su[2][8];
  {
    f4v z = {0.f, 0.f, 0.f, 0.f};
#pragma unroll
    for (int mg = 0; mg < 2; ++mg)
#pragma unroll
      for (int n = 0; n < 8; ++n) su[mg][n] = z;
  }

  auto stage = [&](int h, int buf) {
    int j = h >> 1, hf = h & 1;
    const char* srcA = t1b + (size_t)(IT + j) * 32768 + hf * 16384;
    const char* srcB = lkb + (size_t)(j * (j + 1) / 2 + K) * 32768 + hf * 16384;
    char* dA = (char*)sA + buf * 16384;
    char* dB = (char*)sB + buf * 16384;
#pragma unroll
    for (int it = 0; it < 4; ++it) {
      gld16(srcA + bo + it * 4096, dA + bo + it * 4096);
      gld16(srcB + bo + it * 4096, dB + bo + it * 4096);
    }
  };

  const int h0 = 2 * K, h1 = 2 * I + 1;
  stage(h0, 0);
  for (int h = h0; h <= h1; ++h) {
    int cur = (h - h0) & 1;
    if (h < h1) {
      stage(h + 1, cur ^ 1);
      asm volatile("s_waitcnt vmcnt(8)" ::: "memory");
    } else {
      asm volatile("s_waitcnt vmcnt(0)" ::: "memory");
    }
    __builtin_amdgcn_sched_barrier(0);
    __builtin_amdgcn_s_barrier();
    __builtin_amdgcn_sched_barrier(0);
    const u16* bA = sA + cur * 8192;
    const u16* bB = sB + cur * 8192;
    __builtin_amdgcn_s_setprio(1);
#pragma unroll
    for (int kk = 0; kk < 2; ++kk) {
      int c2 = kk * 32 + g * 8;
      s8v a[2], b[8];
      a[0] = *(const s8v*)(&bA[(w * 32 + l15) * 64 + (c2 ^ sz)]);
      a[1] = *(const s8v*)(&bA[(w * 32 + 16 + l15) * 64 + (c2 ^ sz)]);
#pragma unroll
      for (int n = 0; n < 8; ++n)
        b[n] = *(const s8v*)(&bB[(n * 16 + l15) * 64 + (c2 ^ sz)]);
#pragma unroll
      for (int mg = 0; mg < 2; ++mg)
#pragma unroll
        for (int n = 0; n < 8; ++n)
          su[mg][n] = __builtin_amdgcn_mfma_f32_16x16x32_bf16(a[mg], b[n], su[mg][n], 0, 0, 0);
    }
    __builtin_amdgcn_s_setprio(0);
    __builtin_amdgcn_s_barrier();
  }

  // ---- stage Vs (sB [0,16K)) and Ks (sB [16K,32K)), overlap with silu ----
  {
#pragma unroll
    for (int it = 0; it < 4; ++it) {
      int o = bo + it * 4096;
      int kh = o >> 13, oc = o & 8191;
      int dr = oc >> 7, lo = oc & 127;
      const u16* src = vcT + ((size_t)bh * 64 + dr) * 2048 + K * 128 + kh * 64 +
                       ((lo ^ ((dr & 7) << 4)) >> 1);
      gld16(src, (char*)sB + o);
    }
#pragma unroll
    for (int it = 0; it < 4; ++it) {
      int o = bo + it * 4096;
      int row = o >> 7, lo = o & 127;
      const u16* src = kc + ((size_t)bh * 2048 + K * 128 + row) * 64 +
                       ((lo ^ ((row & 7) << 4)) >> 1);
      gld16(src, (char*)sB + 16384 + o);
    }
  }
#pragma unroll
  for (int mg = 0; mg < 2; ++mg)
#pragma unroll
    for (int n = 0; n < 8; ++n)
#pragma unroll
      for (int j4 = 0; j4 < 4; ++j4) {
        float xv = su[mg][n][j4];
        su[mg][n][j4] = -(xv / (1.f + __expf(-xv)));
      }
  __syncthreads();

  // ---- Sc accumulate ----
#pragma unroll
  for (int kk = 0; kk < 2; ++kk) {
    int c = kk * 32 + g * 8;
    s8v b[8];
#pragma unroll
    for (int n = 0; n < 8; ++n)
      b[n] = *(const s8v*)(&sB[8192 + (n * 16 + l15) * 64 + (c ^ sz)]);
#pragma unroll
    for (int mg = 0; mg < 2; ++mg)
#pragma unroll
      for (int n = 0; n < 8; ++n)
        su[mg][n] = __builtin_amdgcn_mfma_f32_16x16x32_bf16(qa[mg][kk], b[n], su[mg][n], 0, 0, 0);
  }

  if (K == I) {
#pragma unroll
    for (int mg = 0; mg < 2; ++mg)
#pragma unroll
      for (int n = 0; n < 8; ++n)
#pragma unroll
        for (int j4 = 0; j4 < 4; ++j4) {
          int lr = w * 32 + mg * 16 + g * 4 + j4;
          int lc = n * 16 + l15;
          if (lc > lr) su[mg][n][j4] = -3.0e38f;
        }
  }

  // ---- local softmax; P -> sA as [kh][128][64-swz] ----
  float mrow[2][4], lrow[2][4];
#pragma unroll
  for (int mg = 0; mg < 2; ++mg)
#pragma unroll
    for (int j4 = 0; j4 < 4; ++j4) {
      float v = -3.0e38f;
#pragma unroll
      for (int n = 0; n < 8; ++n) v = fmaxf(v, su[mg][n][j4]);
      v = fmaxf(v, __shfl_xor(v, 1));
      v = fmaxf(v, __shfl_xor(v, 2));
      v = fmaxf(v, __shfl_xor(v, 4));
      v = fmaxf(v, __shfl_xor(v, 8));
      mrow[mg][j4] = v;
    }
#pragma unroll
  for (int mg = 0; mg < 2; ++mg)
#pragma unroll
    for (int j4 = 0; j4 < 4; ++j4) {
      float sum = 0.f;
      int prow = w * 32 + mg * 16 + g * 4 + j4;
      int psz = ((g * 4 + j4) & 7) << 3;
#pragma unroll
      for (int n = 0; n < 8; ++n) {
        float e = __expf(su[mg][n][j4] - mrow[mg][j4]);
        sum += e;
        int pc = n * 16 + l15;
        sA[(n >> 2) * 8192 + prow * 64 + ((pc & 63) ^ psz)] = f2bf(e);
      }
      sum += __shfl_xor(sum, 1);
      sum += __shfl_xor(sum, 2);
      sum += __shfl_xor(sum, 4);
      sum += __shfl_xor(sum, 8);
      lrow[mg][j4] = sum;
    }
  __syncthreads();

  // ---- PV: O = P @ Vs ----
  f4v o[2][4];
  {
    f4v z = {0.f, 0.f, 0.f, 0.f};
#pragma unroll
    for (int mg = 0; mg < 2; ++mg)
#pragma unroll
      for (int nd = 0; nd < 4; ++nd) o[mg][nd] = z;
  }
#pragma unroll
  for (int kk = 0; kk < 4; ++kk) {
    int kh = kk >> 1;
    int cc = (kk & 1) * 32 + g * 8;
    s8v pa[2], vb[4];
#pragma unroll
    for (int mg = 0; mg < 2; ++mg)
      pa[mg] = *(const s8v*)(&sA[kh * 8192 + (w * 32 + mg * 16 + l15) * 64 + (cc ^ sz)]);
#pragma unroll
    for (int nd = 0; nd < 4; ++nd)
      vb[nd] = *(const s8v*)(&sB[kh * 4096 + (nd * 16 + l15) * 64 + (cc ^ sz)]);
#pragma unroll
    for (int mg = 0; mg < 2; ++mg)
#pragma unroll
      for (int nd = 0; nd < 4; ++nd)
        o[mg][nd] = __builtin_amdgcn_mfma_f32_16x16x32_bf16(pa[mg], vb[nd], o[mg][nd], 0, 0, 0);
  }

  // ---- write partials ----
  size_t tb = (size_t)lb * 136 + t;
#pragma unroll
  for (int mg = 0; mg < 2; ++mg)
#pragma unroll
    for (int nd = 0; nd < 4; ++nd)
#pragma unroll
      for (int j4 = 0; j4 < 4; ++j4) {
        int prow = w * 32 + mg * 16 + g * 4 + j4;
        int dcol = nd * 16 + l15;
        opart[(tb * 128 + prow) * 64 + dcol] = f2bf(o[mg][nd][j4]);
      }
  if (l15 == 0) {
#pragma unroll
    for (int mg = 0; mg < 2; ++mg)
#pragma unroll
      for (int j4 = 0; j4 < 4; ++j4) {
        int prow = w * 32 + mg * 16 + g * 4 + j4;
        ml[tb * 256 + prow] = mrow[mg][j4];
        ml[tb * 256 + 128 + prow] = lrow[mg][j4];
      }
  }
}

// ------------- combine: flash-merge the <=16 partials per (I, head) -------------

__global__ __launch_bounds__(256) void combine_kernel(const u16* __restrict__ opart,
                                                      const float* __restrict__ ml,
                                                      u16* __restrict__ attn, int c0) {
  int lb = blockIdx.x, I = blockIdx.y, bh = c0 + lb;
  int tid = threadIdx.x;
  int row = tid >> 1, dh = (tid & 1) << 5;
  float M = -3.0e38f, L = 0.f;
  float O[32];
#pragma unroll
  for (int i = 0; i < 32; ++i) O[i] = 0.f;
  for (int K = 0; K <= I; ++K) {
    size_t tb = (size_t)lb * 136 + I * (I + 1) / 2 + K;
    float m = ml[tb * 256 + row];
    float l = ml[tb * 256 + 128 + row];
    float newM = fmaxf(M, m);
    float so = __expf(M - newM), sn = __expf(m - newM);
    L = L * so + l * sn;
    const u16* op = opart + (tb * 128 + row) * 64 + dh;
#pragma unroll
    for (int q = 0; q < 4; ++q) {
      s8v ov = *(const s8v*)(op + q * 8);
#pragma unroll
      for (int e = 0; e < 8; ++e)
        O[q * 8 + e] = O[q * 8 + e] * so + bf2f((u16)ov[e]) * sn;
    }
    M = newM;
  }
  float inv = 1.f / L;
  int b = bh >> 4, hh = bh & 15;
  u16* dst = attn + ((size_t)b * 2048 + I * 128 + row) * 1024 + hh * 64 + dh;
#pragma unroll
  for (int i = 0; i < 32; ++i) dst[i] = f2bf(O[i] * inv);
}

// ------------- final: out = attn_out @ W_out, f32 (gld16 dbuf) -------------

__global__ __launch_bounds__(256, 2) void gemm_out_kernel(const u16* __restrict__ attn,
                                                          const u16* __restrict__ woutT,
                                                          float* __restrict__ out) {
  __shared__ u16 sA[2][8192];
  __shared__ u16 sB[2][8192];
  int bm = blockIdx.x, bn = blockIdx.y;
  int tid = threadIdx.x, lane = tid & 63, w = tid >> 6, wm = w >> 1, wn = w & 1;
  int g = lane >> 4, l15 = lane & 15;
  const int sz = (l15 & 7) << 3;
  const int bo = tid * 16;

  const u16* Ab = attn + (size_t)(bm * 128) * 1024;
  const u16* Bb = woutT + (size_t)(bn * 128) * 1024;

  auto stg = [&](const u16* base, int ks, u16* dst) {
#pragma unroll
    for (int it = 0; it < 4; ++it) {
      int o = bo + it * 4096;
      int row = o >> 7, lo = o & 127;
      gld16(base + (size_t)row * 1024 + ks * 64 + ((lo ^ ((row & 7) << 4)) >> 1),
            (char*)dst + o);
    }
  };

  f4v acc[4][4];
  zero_acc(acc);
  stg(Ab, 0, sA[0]);
  stg(Bb, 0, sB[0]);
  stg(Ab, 1, sA[1]);
  stg(Bb, 1, sB[1]);

  for (int ks = 0; ks < 16; ++ks) {
    int buf = ks & 1;
    if (ks < 15)
      asm volatile("s_waitcnt vmcnt(8)" ::: "memory");
    else
      asm volatile("s_waitcnt vmcnt(0)" ::: "memory");
    __builtin_amdgcn_sched_barrier(0);
    __builtin_amdgcn_s_barrier();
    __builtin_amdgcn_sched_barrier(0);
#pragma unroll
    for (int kk = 0; kk < 2; ++kk) {
      int c2 = kk * 32 + g * 8;
      s8v a[4], b[4];
#pragma unroll
      for (int m = 0; m < 4; ++m)
        a[m] = *(const s8v*)(&sA[buf][(wm * 64 + m * 16 + l15) * 64 + (c2 ^ sz)]);
#pragma unroll
      for (int n = 0; n < 4; ++n)
        b[n] = *(const s8v*)(&sB[buf][(wn * 64 + n * 16 + l15) * 64 + (c2 ^ sz)]);
#pragma unroll
      for (int m = 0; m < 4; ++m)
#pragma unroll
        for (int n = 0; n < 4; ++n)
          acc[m][n] = __builtin_amdgcn_mfma_f32_16x16x32_bf16(a[m], b[n], acc[m][n], 0, 0, 0);
    }
    __builtin_amdgcn_s_barrier();
    if (ks + 2 < 16) {
      stg(Ab, ks + 2, sA[buf]);
      stg(Bb, ks + 2, sB[buf]);
    }
  }

#pragma unroll
  for (int m = 0; m < 4; ++m)
#pragma unroll
    for (int n = 0; n < 4; ++n)
#pragma unroll
      for (int j = 0; j < 4; ++j) {
        int row = bm * 128 + wm * 64 + m * 16 + g * 4 + j;
        int col = bn * 128 + wn * 64 + n * 16 + l15;
        out[(size_t)row * 1024 + col] = acc[m][n][j];
      }
}

// ---------------- host ----------------

extern "C" void kernel_launch(void* const* d_in, const int* in_sizes, int n_in,
                              void* d_out, int out_size, void* d_ws, size_t ws_size,
                              hipStream_t stream) {
  const float* x = (const float*)d_in[0];
  const float* Wqkv = (const float*)d_in[1];
  const float* Wout = (const float*)d_in[2];
  float* out = (float*)d_out;

  char* base = (char*)d_ws;
  size_t off = 0;
  auto alloc = [&](size_t bytes) -> void* {
    void* p = base + off;
    off += (bytes + 255) & ~(size_t)255;
    return p;
  };

  u16* woutT = (u16*)alloc(1024ull * 1024 * 2);
  u16* quS = (u16*)alloc(32ull * 2048 * 64 * 2);
  u16* ku = (u16*)alloc(32ull * 2048 * 64 * 2);
  u16* vu = (u16*)alloc(32ull * 2048 * 64 * 2);
  u16* qcS = (u16*)alloc(32ull * 2048 * 64 * 2);
  u16* kc = (u16*)alloc(32ull * 2048 * 64 * 2);
  u16* vcN = (u16*)alloc(32ull * 2048 * 64 * 2);
  u16* vcT = (u16*)alloc(32ull * 2048 * 64 * 2);
  u16* attn = (u16*)alloc(4096ull * 1024 * 2);

  size_t perBH = 136ull * 16384 * 2 * 2 + 136ull * 128 * 64 * 2 + 136ull * 256 * 4;
  size_t remain = (ws_size > off) ? (ws_size - off) : 0;
  int chunk = (int)(remain / perBH);
  if (chunk < 1) chunk = 1;
  if (chunk > 32) chunk = 32;
  u16* term1p = (u16*)alloc((size_t)chunk * 136 * 16384 * 2);
  u16* lookp = (u16*)alloc((size_t)chunk * 136 * 16384 * 2);
  u16* opart = (u16*)alloc((size_t)chunk * 136 * 8192 * 2);
  float* mlb = (float*)alloc((size_t)chunk * 136 * 256 * 4);

  u16* xb;
  u16* wqkvT;
  if ((size_t)chunk * 136 * 16384 * 2 >= (4096ull + 6144ull) * 1024 * 2) {
    xb = term1p;
    wqkvT = term1p + 4096ull * 1024;
  } else {
    xb = (u16*)alloc(4096ull * 1024 * 2);
    wqkvT = (u16*)alloc(6144ull * 1024 * 2);
  }

  convert_x_kernel<<<4096, 256, 0, stream>>>(x, xb);
  transpose_convert_kernel<<<dim3(192, 32), dim3(32, 8), 0, stream>>>(Wqkv, wqkvT, 1024, 6144);
  transpose_convert_kernel<<<dim3(32, 32), dim3(32, 8), 0, stream>>>(Wout, woutT, 1024, 1024);
  gemm_qkv_kernel<<<dim3(32, 48), 256, 0, stream>>>(xb, wqkvT, quS, ku, vu, qcS, kc, vcN);
  transpose_v_kernel<<<dim3(32, 32), 256, 0, stream>>>(vcN, vcT);

  for (int c0 = 0; c0 < 32; c0 += chunk) {
    int nb = (32 - c0 < chunk) ? (32 - c0) : chunk;
    tl_kernel<<<dim3(136, nb), 256, 0, stream>>>(qcS, vu, quS, ku, term1p, lookp, c0);
    castle_kernel<<<dim3(136 * nb), 256, 0, stream>>>(term1p, lookp, qcS, kc, vcT, opart, mlb, c0);
    combine_kernel<<<dim3(nb, 16), 256, 0, stream>>>(opart, mlb, attn, c0);
  }
  gemm_out_kernel<<<dim3(32, 8), 256, 0, stream>>>(attn, woutT, out);
}

// Round 12
// 496.144 us; speedup vs baseline: 1.6744x; 1.0085x over previous
//
#include <hip/hip_runtime.h>
#include <hip/hip_bf16.h>
#include <stdint.h>

// Castle attention, bf16 MFMA pipeline.
// convert -> qkv GEMM (gld16 dbuf, slab epilogue) -> vcT transpose
//   -> tl (z-merged: one block makes term1(I,K) AND look(K,I))
//   -> castle (2x2-merged: 256x256 score region per block, dbuf j-loop,
//              Su -> -silu -> +Sc -> mask -> 256-wide softmax -> PV partials)
//   -> combine (flash-merge over K-pairs) -> out GEMM (gld16 dbuf).

typedef unsigned short u16;
typedef __attribute__((ext_vector_type(8))) short s8v;   // 8 x bf16
typedef __attribute__((ext_vector_type(4))) float f4v;   // MFMA accumulator

__device__ __forceinline__ u16 f2bf(float f) {
  union { float f; unsigned u; } v; v.f = f;
  unsigned r = v.u + 0x7FFFu + ((v.u >> 16) & 1u);
  return (u16)(r >> 16);
}
__device__ __forceinline__ float bf2f(u16 u) {
  union { unsigned u; float f; } v; v.u = ((unsigned)u) << 16; return v.f;
}

typedef __attribute__((address_space(1))) const void* gas_t;
typedef __attribute__((address_space(3))) void* las_t;
__device__ __forceinline__ void gld16(const void* g, void* l) {
  __builtin_amdgcn_global_load_lds((gas_t)g, (las_t)l, 16, 0, 0);
}

__device__ __forceinline__ void zero_acc(f4v acc[4][4]) {
  f4v z = {0.f, 0.f, 0.f, 0.f};
#pragma unroll
  for (int m = 0; m < 4; ++m)
#pragma unroll
    for (int n = 0; n < 4; ++n) acc[m][n] = z;
}

// ---------------- converts ----------------

__global__ void convert_x_kernel(const float* __restrict__ in, u16* __restrict__ out) {
  int i = (blockIdx.x * 256 + threadIdx.x) * 4;
  float4 v = *(const float4*)(&in[i]);
  out[i + 0] = f2bf(v.x);
  out[i + 1] = f2bf(v.y);
  out[i + 2] = f2bf(v.z);
  out[i + 3] = f2bf(v.w);
}

__global__ void transpose_convert_kernel(const float* __restrict__ in, u16* __restrict__ out,
                                         int R, int C) {
  __shared__ float tile[32][33];
  int c0 = blockIdx.x * 32, r0 = blockIdx.y * 32;
  for (int rr = threadIdx.y; rr < 32; rr += 8)
    tile[rr][threadIdx.x] = in[(size_t)(r0 + rr) * C + (c0 + threadIdx.x)];
  __syncthreads();
  for (int cc = threadIdx.y; cc < 32; cc += 8)
    out[(size_t)(c0 + cc) * R + (r0 + threadIdx.x)] = f2bf(tile[threadIdx.x][cc]);
}

// ---------------- qkv projection: gld16 dbuf staging + LDS slab epilogue ----------------

__global__ __launch_bounds__(256, 2) void gemm_qkv_kernel(
    const u16* __restrict__ xb, const u16* __restrict__ wqkvT,
    u16* __restrict__ quS, u16* __restrict__ ku, u16* __restrict__ vu,
    u16* __restrict__ qcS, u16* __restrict__ kc, u16* __restrict__ vcN) {
  __shared__ u16 sA[2][8192];
  __shared__ u16 sB[2][8192];
  int bm = blockIdx.x, bn = blockIdx.y;
  int tid = threadIdx.x, lane = tid & 63, w = tid >> 6, wm = w >> 1, wn = w & 1;
  int g = lane >> 4, l15 = lane & 15;
  const int sz = (l15 & 7) << 3;
  const int bo = tid * 16;

  const u16* Ab = xb + (size_t)(bm * 128) * 1024;
  const u16* Bb = wqkvT + (size_t)(bn * 128) * 1024;

  auto stg = [&](const u16* base, int ks, u16* dst) {
#pragma unroll
    for (int it = 0; it < 4; ++it) {
      int o = bo + it * 4096;
      int row = o >> 7, lo = o & 127;
      gld16(base + (size_t)row * 1024 + ks * 64 + ((lo ^ ((row & 7) << 4)) >> 1),
            (char*)dst + o);
    }
  };

  f4v acc[4][4];
  zero_acc(acc);
  stg(Ab, 0, sA[0]);
  stg(Bb, 0, sB[0]);
  stg(Ab, 1, sA[1]);
  stg(Bb, 1, sB[1]);

  for (int ks = 0; ks < 16; ++ks) {
    int buf = ks & 1;
    if (ks < 15)
      asm volatile("s_waitcnt vmcnt(8)" ::: "memory");
    else
      asm volatile("s_waitcnt vmcnt(0)" ::: "memory");
    __builtin_amdgcn_sched_barrier(0);
    __builtin_amdgcn_s_barrier();
    __builtin_amdgcn_sched_barrier(0);
#pragma unroll
    for (int kk = 0; kk < 2; ++kk) {
      int c2 = kk * 32 + g * 8;
      s8v a[4], b[4];
#pragma unroll
      for (int m = 0; m < 4; ++m)
        a[m] = *(const s8v*)(&sA[buf][(wm * 64 + m * 16 + l15) * 64 + (c2 ^ sz)]);
#pragma unroll
      for (int n = 0; n < 4; ++n)
        b[n] = *(const s8v*)(&sB[buf][(wn * 64 + n * 16 + l15) * 64 + (c2 ^ sz)]);
#pragma unroll
      for (int m = 0; m < 4; ++m)
#pragma unroll
        for (int n = 0; n < 4; ++n)
          acc[m][n] = __builtin_amdgcn_mfma_f32_16x16x32_bf16(a[m], b[n], acc[m][n], 0, 0, 0);
    }
    __builtin_amdgcn_s_barrier();
    if (ks + 2 < 16) {
      stg(Ab, ks + 2, sA[buf]);
      stg(Bb, ks + 2, sB[buf]);
    }
  }

  int s = bn >> 3;
  int b = bm >> 4;
  int nn0 = (bm & 15) * 128;
  int hh0 = (bn & 7) * 2;
  float scale = (s == 0 || s == 3) ? 0.125f : 1.f;
  u16* obase;
  switch (s) {
    case 0: obase = quS; break;
    case 1: obase = ku; break;
    case 2: obase = vu; break;
    case 3: obase = qcS; break;
    case 4: obase = kc; break;
    default: obase = vcN; break;
  }
  u16* sE = (u16*)sA;
#pragma unroll
  for (int pass = 0; pass < 2; ++pass) {
    __syncthreads();
    if (wn == pass) {
#pragma unroll
      for (int m = 0; m < 4; ++m)
#pragma unroll
        for (int n = 0; n < 4; ++n)
#pragma unroll
          for (int j = 0; j < 4; ++j) {
            int lrow = wm * 64 + m * 16 + g * 4 + j;
            int d = n * 16 + l15;
            sE[lrow * 64 + d] = f2bf(acc[m][n][j] * scale);
          }
    }
    __syncthreads();
    int bh = (b << 4) + hh0 + pass;
    u16* dst = obase + ((size_t)bh * 2048 + nn0) * 64;
    for (int it = 0; it < 4; ++it) {
      int e = (tid + it * 256) * 8;
      *(uint4*)(dst + e) = *(const uint4*)(&sE[e]);
    }
  }
}

// ------------- vcN [bh][n][d] -> vcT [bh][d][n] -------------

__global__ __launch_bounds__(256) void transpose_v_kernel(const u16* __restrict__ vcN,
                                                          u16* __restrict__ vcT) {
  __shared__ u16 t[64][72];
  int nt = blockIdx.x, bh = blockIdx.y;
  const u16* src = vcN + ((size_t)bh * 2048 + nt * 64) * 64;
  int tid = threadIdx.x;
  for (int i = tid; i < 512; i += 256) {
    int r = i >> 3, cseg = i & 7;
    *(uint4*)(&t[r][cseg * 8]) = *(const uint4*)(src + r * 64 + cseg * 8);
  }
  __syncthreads();
  u16* dst = vcT + (size_t)bh * 64 * 2048 + nt * 64;
  for (int i = tid; i < 512; i += 256) {
    int d = i >> 3, nseg = i & 7;
    u16 tmp[8];
#pragma unroll
    for (int e = 0; e < 8; ++e) tmp[e] = t[nseg * 8 + e][d];
    *(uint4*)(dst + (size_t)d * 2048 + nseg * 8) = *(uint4*)tmp;
  }
}

// ------------- tl (z-merged): block (I,K) -> term1(I,K) AND look(K,I) -------------

__global__ __launch_bounds__(256, 2) void tl_kernel(
    const u16* __restrict__ qcS, const u16* __restrict__ vu,
    const u16* __restrict__ quS, const u16* __restrict__ ku,
    u16* __restrict__ term1p, u16* __restrict__ lookp, int c0) {
  __shared__ u16 S[32768];
  int t = blockIdx.x, lb = blockIdx.y, bh = c0 + lb;
  int I = 0;
  while ((I + 1) * (I + 2) / 2 <= t) ++I;
  int K = t - I * (I + 1) / 2;
  int tid = threadIdx.x, lane = tid & 63, w = tid >> 6, wm = w >> 1, wn = w & 1;
  int g = lane >> 4, l15 = lane & 15;
  const int sz = (l15 & 7) << 3;
  const int bo = tid * 16;

  auto stg = [&](const u16* base, int rt, u16* dst) {
#pragma unroll
    for (int it = 0; it < 4; ++it) {
      int o = bo + it * 4096;
      int row = o >> 7, lo = o & 127;
      gld16(base + ((size_t)bh * 2048 + rt * 128 + row) * 64 + ((lo ^ ((row & 7) << 4)) >> 1),
            (char*)dst + o);
    }
  };
  stg(qcS, I, S);
  stg(vu, K, S + 8192);
  stg(quS, K, S + 16384);
  stg(ku, I, S + 24576);

  asm volatile("s_waitcnt vmcnt(0)" ::: "memory");
  __builtin_amdgcn_sched_barrier(0);
  __syncthreads();

  f4v acc1[4][4], acc2[4][4];
  zero_acc(acc1);
  zero_acc(acc2);
#pragma unroll
  for (int kk = 0; kk < 2; ++kk) {
    int c2 = kk * 32 + g * 8;
    s8v a1[4], b1[4], a2[4], b2[4];
#pragma unroll
    for (int m = 0; m < 4; ++m) {
      a1[m] = *(const s8v*)(&S[(wm * 64 + m * 16 + l15) * 64 + (c2 ^ sz)]);
      a2[m] = *(const s8v*)(&S[16384 + (wm * 64 + m * 16 + l15) * 64 + (c2 ^ sz)]);
    }
#pragma unroll
    for (int n = 0; n < 4; ++n) {
      b1[n] = *(const s8v*)(&S[8192 + (wn * 64 + n * 16 + l15) * 64 + (c2 ^ sz)]);
      b2[n] = *(const s8v*)(&S[24576 + (wn * 64 + n * 16 + l15) * 64 + (c2 ^ sz)]);
    }
#pragma unroll
    for (int m = 0; m < 4; ++m)
#pragma unroll
      for (int n = 0; n < 4; ++n) {
        acc1[m][n] = __builtin_amdgcn_mfma_f32_16x16x32_bf16(a1[m], b1[n], acc1[m][n], 0, 0, 0);
        acc2[m][n] = __builtin_amdgcn_mfma_f32_16x16x32_bf16(a2[m], b2[n], acc2[m][n], 0, 0, 0);
      }
  }
  __syncthreads();

#pragma unroll
  for (int m = 0; m < 4; ++m)
#pragma unroll
    for (int n = 0; n < 4; ++n)
#pragma unroll
      for (int j4 = 0; j4 < 4; ++j4) {
        int lr = wm * 64 + m * 16 + g * 4 + j4;
        int lc = wn * 64 + n * 16 + l15;
        int idx = wn * 8192 + lr * 64 + ((lc & 63) ^ ((lr & 7) << 3));
        float v1 = acc1[m][n][j4];
        v1 = ((K * 128 + lc) > (I * 128 + lr)) ? 0.f : v1;
        S[idx] = f2bf(v1);
        float v2 = acc2[m][n][j4];
        v2 = ((I * 128 + lc) > (K * 128 + lr)) ? (1.f / (1.f + __expf(-v2))) : 0.f;
        S[16384 + idx] = f2bf(v2);
      }
  __syncthreads();

  u16* o1 = term1p + ((size_t)lb * 136 + t) * 16384;
  u16* o2 = lookp + ((size_t)lb * 136 + t) * 16384;
#pragma unroll
  for (int it = 0; it < 8; ++it) {
    int e = (tid + it * 256) * 8;
    *(uint4*)(o1 + e) = *(const uint4*)(&S[e]);
    *(uint4*)(o2 + e) = *(const uint4*)(&S[16384 + e]);
  }
}

// ------------- castle (2x2-merged): 256x256 score region per block -------------
// waves: w in [0,8): rhalf = w>>2 (I sub-tile), rsub = w&3 (32-row slice).
// j-loop stages 4 half-tiles (64 KB) per step, dbuf (128 KB LDS).
// Tail: Ks/Vs staged; Sc; unified mask; 256-wide softmax; wave-private P chunks; PV.

__global__ __launch_bounds__(512, 1) void castle_kernel(
    const u16* __restrict__ term1p, const u16* __restrict__ lookp,
    const u16* __restrict__ qcS, const u16* __restrict__ kc,
    const u16* __restrict__ vcT, const u16* __restrict__ ztile,
    u16* __restrict__ opart, float* __restrict__ ml, int c0) {
  __shared__ u16 S[65536];  // 128 KB
  int bid = blockIdx.x;
  int lb = bid / 36, sid = bid % 36;
  int bh = c0 + lb;
  // decode (Ip,Kp) with d = Ip-Kp descending (heaviest first)
  int d = 7, rem = sid;
  while (rem >= 8 - d) { rem -= 8 - d; --d; }
  int Kp = rem, Ip = Kp + d;

  int tid = threadIdx.x, lane = tid & 63, w = tid >> 6;
  int g = lane >> 4, l15 = lane & 15;
  const int sz = (l15 & 7) << 3;
  int rhalf = w >> 2, rsub = w & 3;
  int i_t = 2 * Ip + rhalf;      // this wave's I tile
  int rowbase = rsub * 32;       // row slice within the 128-row tile
  const int bo = tid * 16;       // 512 threads x 16 B = 8 KB per staging round

  const char* t1b = (const char*)(term1p + (size_t)lb * 136 * 16384);
  const char* lkb = (const char*)(lookp + (size_t)lb * 136 * 16384);

  // qc A-frags for Sc (wave's 32 rows of tile i_t)
  s8v qa[2][2];
#pragma unroll
  for (int mg = 0; mg < 2; ++mg)
#pragma unroll
    for (int kk = 0; kk < 2; ++kk)
      qa[mg][kk] = *(const s8v*)(&qcS[((size_t)bh * 2048 + i_t * 128 + rowbase + mg * 16 + l15) *
                                          64 + kk * 32 + g * 8]);

  f4v su[2][16];
  {
    f4v z = {0.f, 0.f, 0.f, 0.f};
#pragma unroll
    for (int mg = 0; mg < 2; ++mg)
#pragma unroll
      for (int n = 0; n < 16; ++n) su[mg][n] = z;
  }

  // stage j-half h into buffer buf: 4 half-tiles, 8 gld16/thread
  auto stage = [&](int h, int buf) {
    int jt = h >> 1, hf = h & 1;
    const char* a0 = (jt <= 2 * Ip)
                         ? t1b + (size_t)(2 * Ip * (2 * Ip + 1) / 2 + jt) * 32768 + hf * 16384
                         : (const char*)ztile;
    const char* a1 = t1b + (size_t)((2 * Ip + 1) * (2 * Ip + 2) / 2 + jt) * 32768 + hf * 16384;
    const char* b0 = lkb + (size_t)(jt * (jt + 1) / 2 + 2 * Kp) * 32768 + hf * 16384;
    const char* b1 = (jt >= 2 * Kp + 1)
                         ? lkb + (size_t)(jt * (jt + 1) / 2 + 2 * Kp + 1) * 32768 + hf * 16384
                         : (const char*)ztile;
    char* dst = (char*)S + buf * 65536;
#pragma unroll
    for (int r = 0; r < 2; ++r) {
      gld16(a0 + bo + r * 8192, dst + bo + r * 8192);
      gld16(a1 + bo + r * 8192, dst + 16384 + bo + r * 8192);
      gld16(b0 + bo + r * 8192, dst + 32768 + bo + r * 8192);
      gld16(b1 + bo + r * 8192, dst + 49152 + bo + r * 8192);
    }
  };

  const int h0 = 4 * Kp, h1 = 4 * Ip + 3;
  stage(h0, 0);
  for (int h = h0; h <= h1; ++h) {
    int cur = (h - h0) & 1;
    if (h < h1) {
      stage(h + 1, cur ^ 1);
      asm volatile("s_waitcnt vmcnt(8)" ::: "memory");
    } else {
      asm volatile("s_waitcnt vmcnt(0)" ::: "memory");
    }
    __builtin_amdgcn_sched_barrier(0);
    __builtin_amdgcn_s_barrier();
    __builtin_amdgcn_sched_barrier(0);
    const u16* TA = S + cur * 32768 + rhalf * 8192;   // this wave's term1 half-tile
    const u16* LB = S + cur * 32768 + 16384;          // both look half-tiles
    __builtin_amdgcn_s_setprio(1);
#pragma unroll
    for (int kk = 0; kk < 2; ++kk) {
      int c2 = kk * 32 + g * 8;
      s8v a[2];
      a[0] = *(const s8v*)(&TA[(rowbase + l15) * 64 + (c2 ^ sz)]);
      a[1] = *(const s8v*)(&TA[(rowbase + 16 + l15) * 64 + (c2 ^ sz)]);
#pragma unroll
      for (int n = 0; n < 16; ++n) {
        s8v b = *(const s8v*)(&LB[(n >> 3) * 8192 + ((n & 7) * 16 + l15) * 64 + (c2 ^ sz)]);
        su[0][n] = __builtin_amdgcn_mfma_f32_16x16x32_bf16(a[0], b, su[0][n], 0, 0, 0);
        su[1][n] = __builtin_amdgcn_mfma_f32_16x16x32_bf16(a[1], b, su[1][n], 0, 0, 0);
      }
    }
    __builtin_amdgcn_s_setprio(0);
    __builtin_amdgcn_s_barrier();
  }

  // ---- stage Ks (256x64) at elems [0,16384) and Vs [kq(4)][64d][64k] at [16384,32768) ----
  {
#pragma unroll
    for (int it = 0; it < 4; ++it) {
      int o = bo + it * 8192;            // [0, 32768) bytes
      int row = o >> 7, lo = o & 127;    // row in [0,256)
      const u16* src = kc + ((size_t)bh * 2048 + Kp * 256 + row) * 64 +
                       ((lo ^ ((row & 7) << 4)) >> 1);
      gld16(src, (char*)S + o);
    }
#pragma unroll
    for (int it = 0; it < 4; ++it) {
      int o = bo + it * 8192;
      int kq = o >> 13, oc = o & 8191;
      int dr = oc >> 7, lo = oc & 127;
      const u16* src = vcT + ((size_t)bh * 64 + dr) * 2048 + Kp * 256 + kq * 64 +
                       ((lo ^ ((dr & 7) << 4)) >> 1);
      gld16(src, (char*)S + 32768 + o);
    }
  }
  // su = -silu(su) while loads fly
#pragma unroll
  for (int mg = 0; mg < 2; ++mg)
#pragma unroll
    for (int n = 0; n < 16; ++n)
#pragma unroll
      for (int j4 = 0; j4 < 4; ++j4) {
        float xv = su[mg][n][j4];
        su[mg][n][j4] = -(xv / (1.f + __expf(-xv)));
      }
  __syncthreads();  // drains vmcnt: Ks/Vs ready

  // ---- Sc accumulate (Ks at elems [0,16384), 256 rows x 64 d) ----
#pragma unroll
  for (int kk = 0; kk < 2; ++kk) {
    int c = kk * 32 + g * 8;
#pragma unroll
    for (int n = 0; n < 16; ++n) {
      s8v b = *(const s8v*)(&S[(n * 16 + l15) * 64 + (c ^ sz)]);
      su[0][n] = __builtin_amdgcn_mfma_f32_16x16x32_bf16(qa[0][kk], b, su[0][n], 0, 0, 0);
      su[1][n] = __builtin_amdgcn_mfma_f32_16x16x32_bf16(qa[1][kk], b, su[1][n], 0, 0, 0);
    }
  }

  // ---- unified causal mask: gcol > grow -> -inf ----
#pragma unroll
  for (int mg = 0; mg < 2; ++mg)
#pragma unroll
    for (int n = 0; n < 16; ++n)
#pragma unroll
      for (int j4 = 0; j4 < 4; ++j4) {
        int grow = i_t * 128 + rowbase + mg * 16 + g * 4 + j4;
        int gcol = Kp * 256 + n * 16 + l15;
        if (gcol > grow) su[mg][n][j4] = -3.0e38f;
      }

  // ---- 256-wide local softmax: m, l per row; su <- exp(su - m) ----
  float mrow[2][4], lrow[2][4];
#pragma unroll
  for (int mg = 0; mg < 2; ++mg)
#pragma unroll
    for (int j4 = 0; j4 < 4; ++j4) {
      float v = -3.0e38f;
#pragma unroll
      for (int n = 0; n < 16; ++n) v = fmaxf(v, su[mg][n][j4]);
      v = fmaxf(v, __shfl_xor(v, 1));
      v = fmaxf(v, __shfl_xor(v, 2));
      v = fmaxf(v, __shfl_xor(v, 4));
      v = fmaxf(v, __shfl_xor(v, 8));
      mrow[mg][j4] = v;
      float sum = 0.f;
#pragma unroll
      for (int n = 0; n < 16; ++n) {
        float e = __expf(su[mg][n][j4] - v);
        su[mg][n][j4] = e;
        sum += e;
      }
      sum += __shfl_xor(sum, 1);
      sum += __shfl_xor(sum, 2);
      sum += __shfl_xor(sum, 4);
      sum += __shfl_xor(sum, 8);
      lrow[mg][j4] = sum;
    }

  // ---- PV via wave-private P chunks: O = P @ Vs, kq in [0,4) ----
  f4v o[2][4];
  {
    f4v z = {0.f, 0.f, 0.f, 0.f};
#pragma unroll
    for (int mg = 0; mg < 2; ++mg)
#pragma unroll
      for (int nd = 0; nd < 4; ++nd) o[mg][nd] = z;
  }
  u16* Pw = S + 32768 + w * 2048;  // wave-private 32x64 chunk (4 KB)
#pragma unroll
  for (int kq = 0; kq < 4; ++kq) {
    // write this wave's P chunk (rows 32, cols 64) swizzled
#pragma unroll
    for (int mg = 0; mg < 2; ++mg)
#pragma unroll
      for (int j4 = 0; j4 < 4; ++j4) {
        int rl = mg * 16 + g * 4 + j4;
        int psz = (rl & 7) << 3;
#pragma unroll
        for (int nn = 0; nn < 4; ++nn) {
          int pc = nn * 16 + l15;
          Pw[rl * 64 + (pc ^ psz)] = f2bf(su[mg][kq * 4 + nn][j4]);
        }
      }
    asm volatile("s_waitcnt lgkmcnt(0)" ::: "memory");
    __builtin_amdgcn_sched_barrier(0);
#pragma unroll
    for (int kk = 0; kk < 2; ++kk) {
      int c = kk * 32 + g * 8;
      s8v pa[2], vb[4];
      pa[0] = *(const s8v*)(&Pw[(l15) * 64 + (c ^ sz)]);
      pa[1] = *(const s8v*)(&Pw[(16 + l15) * 64 + (c ^ sz)]);
#pragma unroll
      for (int nd = 0; nd < 4; ++nd)
        vb[nd] = *(const s8v*)(&S[16384 + kq * 4096 + (nd * 16 + l15) * 64 + (c ^ sz)]);
#pragma unroll
      for (int mg = 0; mg < 2; ++mg)
#pragma unroll
        for (int nd = 0; nd < 4; ++nd)
          o[mg][nd] = __builtin_amdgcn_mfma_f32_16x16x32_bf16(pa[mg], vb[nd], o[mg][nd], 0, 0, 0);
    }
  }

  // ---- write partials: pidx = i_t*8 + Kp ----
  size_t tb = (size_t)lb * 128 + i_t * 8 + Kp;
#pragma unroll
  for (int mg = 0; mg < 2; ++mg)
#pragma unroll
    for (int nd = 0; nd < 4; ++nd)
#pragma unroll
      for (int j4 = 0; j4 < 4; ++j4) {
        int prow = rowbase + mg * 16 + g * 4 + j4;
        int dcol = nd * 16 + l15;
        opart[(tb * 128 + prow) * 64 + dcol] = f2bf(o[mg][nd][j4]);
      }
  if (l15 == 0) {
#pragma unroll
    for (int mg = 0; mg < 2; ++mg)
#pragma unroll
      for (int j4 = 0; j4 < 4; ++j4) {
        int prow = rowbase + mg * 16 + g * 4 + j4;
        ml[tb * 256 + prow] = mrow[mg][j4];
        ml[tb * 256 + 128 + prow] = lrow[mg][j4];
      }
  }
}

// ------------- combine: flash-merge the <=8 K-pair partials per (I, head) -------------

__global__ __launch_bounds__(256) void combine_kernel(const u16* __restrict__ opart,
                                                      const float* __restrict__ ml,
                                                      u16* __restrict__ attn, int c0) {
  int lb = blockIdx.x, I = blockIdx.y, bh = c0 + lb;
  int tid = threadIdx.x;
  int row = tid >> 1, dh = (tid & 1) << 5;
  float M = -3.0e38f, L = 0.f;
  float O[32];
#pragma unroll
  for (int i = 0; i < 32; ++i) O[i] = 0.f;
  int kmax = I >> 1;
  for (int K = 0; K <= kmax; ++K) {
    size_t tb = (size_t)lb * 128 + I * 8 + K;
    float m = ml[tb * 256 + row];
    float l = ml[tb * 256 + 128 + row];
    float newM = fmaxf(M, m);
    float so = __expf(M - newM), sn = __expf(m - newM);
    L = L * so + l * sn;
    const u16* op = opart + (tb * 128 + row) * 64 + dh;
#pragma unroll
    for (int q = 0; q < 4; ++q) {
      s8v ov = *(const s8v*)(op + q * 8);
#pragma unroll
      for (int e = 0; e < 8; ++e)
        O[q * 8 + e] = O[q * 8 + e] * so + bf2f((u16)ov[e]) * sn;
    }
    M = newM;
  }
  float inv = 1.f / L;
  int b = bh >> 4, hh = bh & 15;
  u16* dst = attn + ((size_t)b * 2048 + I * 128 + row) * 1024 + hh * 64 + dh;
#pragma unroll
  for (int i = 0; i < 32; ++i) dst[i] = f2bf(O[i] * inv);
}

// ------------- final: out = attn_out @ W_out, f32 (gld16 dbuf) -------------

__global__ __launch_bounds__(256, 2) void gemm_out_kernel(const u16* __restrict__ attn,
                                                          const u16* __restrict__ woutT,
                                                          float* __restrict__ out) {
  __shared__ u16 sA[2][8192];
  __shared__ u16 sB[2][8192];
  int bm = blockIdx.x, bn = blockIdx.y;
  int tid = threadIdx.x, lane = tid & 63, w = tid >> 6, wm = w >> 1, wn = w & 1;
  int g = lane >> 4, l15 = lane & 15;
  const int sz = (l15 & 7) << 3;
  const int bo = tid * 16;

  const u16* Ab = attn + (size_t)(bm * 128) * 1024;
  const u16* Bb = woutT + (size_t)(bn * 128) * 1024;

  auto stg = [&](const u16* base, int ks, u16* dst) {
#pragma unroll
    for (int it = 0; it < 4; ++it) {
      int o = bo + it * 4096;
      int row = o >> 7, lo = o & 127;
      gld16(base + (size_t)row * 1024 + ks * 64 + ((lo ^ ((row & 7) << 4)) >> 1),
            (char*)dst + o);
    }
  };

  f4v acc[4][4];
  zero_acc(acc);
  stg(Ab, 0, sA[0]);
  stg(Bb, 0, sB[0]);
  stg(Ab, 1, sA[1]);
  stg(Bb, 1, sB[1]);

  for (int ks = 0; ks < 16; ++ks) {
    int buf = ks & 1;
    if (ks < 15)
      asm volatile("s_waitcnt vmcnt(8)" ::: "memory");
    else
      asm volatile("s_waitcnt vmcnt(0)" ::: "memory");
    __builtin_amdgcn_sched_barrier(0);
    __builtin_amdgcn_s_barrier();
    __builtin_amdgcn_sched_barrier(0);
#pragma unroll
    for (int kk = 0; kk < 2; ++kk) {
      int c2 = kk * 32 + g * 8;
      s8v a[4], b[4];
#pragma unroll
      for (int m = 0; m < 4; ++m)
        a[m] = *(const s8v*)(&sA[buf][(wm * 64 + m * 16 + l15) * 64 + (c2 ^ sz)]);
#pragma unroll
      for (int n = 0; n < 4; ++n)
        b[n] = *(const s8v*)(&sB[buf][(wn * 64 + n * 16 + l15) * 64 + (c2 ^ sz)]);
#pragma unroll
      for (int m = 0; m < 4; ++m)
#pragma unroll
        for (int n = 0; n < 4; ++n)
          acc[m][n] = __builtin_amdgcn_mfma_f32_16x16x32_bf16(a[m], b[n], acc[m][n], 0, 0, 0);
    }
    __builtin_amdgcn_s_barrier();
    if (ks + 2 < 16) {
      stg(Ab, ks + 2, sA[buf]);
      stg(Bb, ks + 2, sB[buf]);
    }
  }

#pragma unroll
  for (int m = 0; m < 4; ++m)
#pragma unroll
    for (int n = 0; n < 4; ++n)
#pragma unroll
      for (int j = 0; j < 4; ++j) {
        int row = bm * 128 + wm * 64 + m * 16 + g * 4 + j;
        int col = bn * 128 + wn * 64 + n * 16 + l15;
        out[(size_t)row * 1024 + col] = acc[m][n][j];
      }
}

// ---------------- host ----------------

extern "C" void kernel_launch(void* const* d_in, const int* in_sizes, int n_in,
                              void* d_out, int out_size, void* d_ws, size_t ws_size,
                              hipStream_t stream) {
  const float* x = (const float*)d_in[0];
  const float* Wqkv = (const float*)d_in[1];
  const float* Wout = (const float*)d_in[2];
  float* out = (float*)d_out;

  char* base = (char*)d_ws;
  size_t off = 0;
  auto alloc = [&](size_t bytes) -> void* {
    void* p = base + off;
    off += (bytes + 255) & ~(size_t)255;
    return p;
  };

  u16* woutT = (u16*)alloc(1024ull * 1024 * 2);
  u16* quS = (u16*)alloc(32ull * 2048 * 64 * 2);
  u16* ku = (u16*)alloc(32ull * 2048 * 64 * 2);
  u16* vu = (u16*)alloc(32ull * 2048 * 64 * 2);
  u16* qcS = (u16*)alloc(32ull * 2048 * 64 * 2);
  u16* kc = (u16*)alloc(32ull * 2048 * 64 * 2);
  u16* vcN = (u16*)alloc(32ull * 2048 * 64 * 2);
  u16* vcT = (u16*)alloc(32ull * 2048 * 64 * 2);
  u16* attn = (u16*)alloc(4096ull * 1024 * 2);
  u16* ztile = (u16*)alloc(16384);  // 16 KB zero tile for out-of-triangle reads

  size_t perBH = 136ull * 16384 * 2 * 2 + 128ull * 128 * 64 * 2 + 128ull * 256 * 4;
  size_t remain = (ws_size > off) ? (ws_size - off) : 0;
  int chunk = (int)(remain / perBH);
  if (chunk < 1) chunk = 1;
  if (chunk > 32) chunk = 32;
  u16* term1p = (u16*)alloc((size_t)chunk * 136 * 16384 * 2);
  u16* lookp = (u16*)alloc((size_t)chunk * 136 * 16384 * 2);
  u16* opart = (u16*)alloc((size_t)chunk * 128 * 8192 * 2);
  float* mlb = (float*)alloc((size_t)chunk * 128 * 256 * 4);

  u16* xb;
  u16* wqkvT;
  if ((size_t)chunk * 136 * 16384 * 2 >= (4096ull + 6144ull) * 1024 * 2) {
    xb = term1p;
    wqkvT = term1p + 4096ull * 1024;
  } else {
    xb = (u16*)alloc(4096ull * 1024 * 2);
    wqkvT = (u16*)alloc(6144ull * 1024 * 2);
  }

  hipMemsetAsync(ztile, 0, 16384, stream);
  convert_x_kernel<<<4096, 256, 0, stream>>>(x, xb);
  transpose_convert_kernel<<<dim3(192, 32), dim3(32, 8), 0, stream>>>(Wqkv, wqkvT, 1024, 6144);
  transpose_convert_kernel<<<dim3(32, 32), dim3(32, 8), 0, stream>>>(Wout, woutT, 1024, 1024);
  gemm_qkv_kernel<<<dim3(32, 48), 256, 0, stream>>>(xb, wqkvT, quS, ku, vu, qcS, kc, vcN);
  transpose_v_kernel<<<dim3(32, 32), 256, 0, stream>>>(vcN, vcT);

  for (int c0 = 0; c0 < 32; c0 += chunk) {
    int nb = (32 - c0 < chunk) ? (32 - c0) : chunk;
    tl_kernel<<<dim3(136, nb), 256, 0, stream>>>(qcS, vu, quS, ku, term1p, lookp, c0);
    castle_kernel<<<dim3(36 * nb), 512, 0, stream>>>(term1p, lookp, qcS, kc, vcT, ztile,
                                                     opart, mlb, c0);
    combine_kernel<<<dim3(nb, 16), 256, 0, stream>>>(opart, mlb, attn, c0);
  }
  gemm_out_kernel<<<dim3(32, 8), 256, 0, stream>>>(attn, woutT, out);
}